// Round 1
// baseline (94.096 us; speedup 1.0000x reference)
//
#include <hip/hip_runtime.h>
#include <cmath>
#include <cstdint>
#include <cstddef>

using u32 = unsigned int;

// ---------------- compile-time geometry ----------------
// levels n = [4,4,5,6,8,10,12,14,17,21,25,30,36,44,53,63/64]
// kh = 64//n = [16,16,12,10,8,6,5,4,3,3,2,2,1,1,1,1]
// grid res nh = 64//kh (levels 0..11; levels 12..15 are identity, nh=64)
constexpr int NH[12] = {4,4,5,6,8,10,12,16,21,21,32,32};

// float offsets of max-pool grids in ws  (layout [4][3][nh][nh][nh])
constexpr int OFF_M2  = 0;        // 32^3 *12 = 393216
constexpr int OFF_M3  = 393216;   // 21^3 *12 = 111132
constexpr int OFF_M5  = 504348;   // 12^3 *12 = 20736
constexpr int OFF_M4  = 525084;   // 16^3 *12 = 49152
constexpr int OFF_M6  = 574236;   // 10^3 *12 = 12000
constexpr int OFF_M8  = 586236;   //  8^3 *12 = 6144
constexpr int OFF_M10 = 592380;   //  6^3 *12 = 2592
constexpr int OFF_M12 = 594972;   //  5^3 *12 = 1500
constexpr int OFF_M16 = 596472;   //  4^3 *12 = 768  -> end 597240 (mult of 4)

// feature grids (float4), layout [b][p][r][q], offsets in float4 units
constexpr int GOFF[12] = {149310,149566,149822,150322,151186,153234,
                          157234,164146,180530,217574,254618,385690};
// total ws need: 516762 float4 = 8.27 MB

constexpr float invf_of(int nh){ return (float)(1.0/(64.0/(double)nh)); }
constexpr float INVF[12] = {invf_of(4),invf_of(4),invf_of(5),invf_of(6),
                            invf_of(8),invf_of(10),invf_of(12),invf_of(16),
                            invf_of(21),invf_of(21),invf_of(32),invf_of(32)};

struct HP { int n[16]; };

// ---------------- helpers ----------------
__device__ inline float lp(float a, float b, float w){ return fmaf(w, b - a, a); }

__device__ inline void hash_store(const float* __restrict__ tbl, float4* __restrict__ g4,
                                  int goff, int lvl, int n,
                                  float m0, float m1, float m2, int idx)
{
    float nf = (float)n;
    u32 g0 = (u32)(m0 * nf);
    u32 g1 = ((u32)(m1 * nf)) * 2654435761u;
    u32 g2 = ((u32)(m2 * nf)) * 805459861u;
    u32 h  = (g0 ^ g1 ^ g2) & 255u;
    const float* te = tbl + ((size_t)lvl * 256 + h) * 3;
    g4[goff + idx] = make_float4(te[0], te[1], te[2], 0.0f);
}

// ---------------- K1: base max-pools M2, M3, M5 from x ----------------
// threads: M2 [0,393216), M3 [393216,504348), M5 [504348,525084)
__global__ __launch_bounds__(256) void k_pool_base(const float* __restrict__ x,
                                                   float* __restrict__ ws)
{
    int tid = blockIdx.x * 256 + threadIdx.x;
    if (tid < 393216) {                       // M2: 2^3 windows
        int pd = tid & 31, pw = (tid >> 5) & 31, ph = (tid >> 10) & 31;
        int bc = tid >> 15;                   // [0,12)
        const float* xp = x + (size_t)bc * 262144 + (ph*2)*4096 + (pw*2)*64 + pd*2;
        float2 v00 = *(const float2*)(xp);
        float2 v01 = *(const float2*)(xp + 64);
        float2 v10 = *(const float2*)(xp + 4096);
        float2 v11 = *(const float2*)(xp + 4160);
        float m = fmaxf(fmaxf(fmaxf(v00.x,v00.y), fmaxf(v01.x,v01.y)),
                        fmaxf(fmaxf(v10.x,v10.y), fmaxf(v11.x,v11.y)));
        ws[OFF_M2 + tid] = m;
    } else if (tid < 504348) {                // M3: 3^3 windows
        int idx = tid - 393216;
        int pd = idx % 21; int t2 = idx / 21;
        int pw = t2 % 21;  int t3 = t2 / 21;
        int ph = t3 % 21;  int bc = t3 / 21;
        const float* xp = x + (size_t)bc * 262144 + (ph*3)*4096 + (pw*3)*64 + pd*3;
        float m = -1.f;
        #pragma unroll
        for (int dh = 0; dh < 3; ++dh)
        #pragma unroll
        for (int dw = 0; dw < 3; ++dw) {
            const float* r = xp + dh*4096 + dw*64;
            m = fmaxf(m, fmaxf(fmaxf(r[0], r[1]), r[2]));
        }
        ws[OFF_M3 + idx] = m;
    } else if (tid < 525084) {                // M5: 5^3 windows
        int idx = tid - 504348;
        int pd = idx % 12; int t2 = idx / 12;
        int pw = t2 % 12;  int t3 = t2 / 12;
        int ph = t3 % 12;  int bc = t3 / 12;
        const float* xp = x + (size_t)bc * 262144 + (ph*5)*4096 + (pw*5)*64 + pd*5;
        float m = -1.f;
        #pragma unroll
        for (int dh = 0; dh < 5; ++dh)
        #pragma unroll
        for (int dw = 0; dw < 5; ++dw) {
            const float* r = xp + dh*4096 + dw*64;
            m = fmaxf(m, fmaxf(fmaxf(fmaxf(r[0],r[1]), fmaxf(r[2],r[3])), r[4]));
        }
        ws[OFF_M5 + idx] = m;
    }
}

// ---------------- K2: pyramid grids + gathers for levels 8..11 ----------------
// ranges: M16-wave [0,49152), M4 [49152,98304), M6 [98304,110304),
//         M8 [110304,116448), M10 [116448,119040), M12 [119040,120540),
//         L10/11 [120540,251612), L8/9 [251612,288656)
__global__ __launch_bounds__(256) void k_pyr(const float* __restrict__ tbl,
                                             float* __restrict__ ws, HP hp)
{
    int tid = blockIdx.x * 256 + threadIdx.x;
    float4* g4 = (float4*)ws;
    if (tid < 49152) {                        // M16: wave per cell, 8^3 over M2
        int w = tid >> 6, lane = tid & 63;
        int pd = w & 3, pw = (w >> 2) & 3, ph = (w >> 4) & 3, bc = w >> 6;
        const float* m2 = ws + OFF_M2 + (size_t)bc*32768 + (ph*8)*1024 + (pw*8)*32 + pd*8;
        float m = -1.f;
        #pragma unroll
        for (int e = 0; e < 8; ++e) {
            int id2 = (e << 6) | lane;        // 0..511
            int dd = id2 & 7, dw = (id2 >> 3) & 7, dh = id2 >> 6;
            m = fmaxf(m, m2[dh*1024 + dw*32 + dd]);
        }
        #pragma unroll
        for (int s = 32; s; s >>= 1) m = fmaxf(m, __shfl_xor(m, s, 64));
        if (lane == 0) ws[OFF_M16 + w] = m;
    } else if (tid < 98304) {                 // M4: 2^3 over M2
        int idx = tid - 49152;
        int pd = idx & 15, pw = (idx >> 4) & 15, ph = (idx >> 8) & 15, bc = idx >> 12;
        const float* m2 = ws + OFF_M2 + (size_t)bc*32768 + (ph*2)*1024 + (pw*2)*32 + pd*2;
        float2 u0 = *(const float2*)(m2);
        float2 u1 = *(const float2*)(m2 + 32);
        float2 u2 = *(const float2*)(m2 + 1024);
        float2 u3 = *(const float2*)(m2 + 1056);
        ws[OFF_M4 + idx] = fmaxf(fmaxf(fmaxf(u0.x,u0.y), fmaxf(u1.x,u1.y)),
                                 fmaxf(fmaxf(u2.x,u2.y), fmaxf(u3.x,u3.y)));
    } else if (tid < 110304) {                // M6: 3^3 over M2
        int idx = tid - 98304;
        int pd = idx % 10; int t2 = idx / 10;
        int pw = t2 % 10;  int t3 = t2 / 10;
        int ph = t3 % 10;  int bc = t3 / 10;
        const float* m2 = ws + OFF_M2 + (size_t)bc*32768 + (ph*3)*1024 + (pw*3)*32 + pd*3;
        float m = -1.f;
        #pragma unroll
        for (int dh = 0; dh < 3; ++dh)
        #pragma unroll
        for (int dw = 0; dw < 3; ++dw) {
            const float* r = m2 + dh*1024 + dw*32;
            m = fmaxf(m, fmaxf(fmaxf(r[0], r[1]), r[2]));
        }
        ws[OFF_M6 + idx] = m;
    } else if (tid < 116448) {                // M8: 4^3 over M2
        int idx = tid - 110304;
        int pd = idx & 7, pw = (idx >> 3) & 7, ph = (idx >> 6) & 7, bc = idx >> 9;
        const float* m2 = ws + OFF_M2 + (size_t)bc*32768 + (ph*4)*1024 + (pw*4)*32 + pd*4;
        float m = -1.f;
        #pragma unroll
        for (int dh = 0; dh < 4; ++dh)
        #pragma unroll
        for (int dw = 0; dw < 4; ++dw) {
            float4 v = *(const float4*)(m2 + dh*1024 + dw*32);
            m = fmaxf(m, fmaxf(fmaxf(v.x,v.y), fmaxf(v.z,v.w)));
        }
        ws[OFF_M8 + idx] = m;
    } else if (tid < 119040) {                // M10: 5^3 over M2
        int idx = tid - 116448;
        int pd = idx % 6; int t2 = idx / 6;
        int pw = t2 % 6;  int t3 = t2 / 6;
        int ph = t3 % 6;  int bc = t3 / 6;
        const float* m2 = ws + OFF_M2 + (size_t)bc*32768 + (ph*5)*1024 + (pw*5)*32 + pd*5;
        float m = -1.f;
        #pragma unroll
        for (int dh = 0; dh < 5; ++dh)
        #pragma unroll
        for (int dw = 0; dw < 5; ++dw) {
            const float* r = m2 + dh*1024 + dw*32;
            m = fmaxf(m, fmaxf(fmaxf(fmaxf(r[0],r[1]), fmaxf(r[2],r[3])), r[4]));
        }
        ws[OFF_M10 + idx] = m;
    } else if (tid < 120540) {                // M12: 4^3 over M3
        int idx = tid - 119040;
        int pd = idx % 5; int t2 = idx / 5;
        int pw = t2 % 5;  int t3 = t2 / 5;
        int ph = t3 % 5;  int bc = t3 / 5;
        const float* m3 = ws + OFF_M3 + (size_t)bc*9261 + (ph*4)*441 + (pw*4)*21 + pd*4;
        float m = -1.f;
        #pragma unroll
        for (int dh = 0; dh < 4; ++dh)
        #pragma unroll
        for (int dw = 0; dw < 4; ++dw) {
            const float* r = m3 + dh*441 + dw*21;
            m = fmaxf(m, fmaxf(fmaxf(r[0],r[1]), fmaxf(r[2],r[3])));
        }
        ws[OFF_M12 + idx] = m;
    } else if (tid < 251612) {                // gather L10,L11 from M2 (nh=32)
        int idx = tid - 120540;
        int q = idx & 31, r = (idx >> 5) & 31, p = (idx >> 10) & 31, b = idx >> 15;
        int o = (p << 10) + (q << 5) + r;     // M[b][c][p][q][r]
        const float* M = ws + OFF_M2 + (size_t)b * 98304;
        float m0 = M[o], m1 = M[o + 32768], m2 = M[o + 65536];
        hash_store(tbl, g4, GOFF[10], 10, hp.n[10], m0, m1, m2, idx);
        hash_store(tbl, g4, GOFF[11], 11, hp.n[11], m0, m1, m2, idx);
    } else if (tid < 288656) {                // gather L8,L9 from M3 (nh=21)
        int idx = tid - 251612;
        int q = idx % 21; int t2 = idx / 21;
        int r = t2 % 21;  int t3 = t2 / 21;
        int p = t3 % 21;  int b = t3 / 21;
        int o = p*441 + q*21 + r;
        const float* M = ws + OFF_M3 + (size_t)b * 27783;
        float m0 = M[o], m1 = M[o + 9261], m2 = M[o + 18522];
        hash_store(tbl, g4, GOFF[8], 8, hp.n[8], m0, m1, m2, idx);
        hash_store(tbl, g4, GOFF[9], 9, hp.n[9], m0, m1, m2, idx);
    }
}

// ---------------- K3: gathers for levels 0..7 ----------------
__global__ __launch_bounds__(256) void k_gather_small(const float* __restrict__ tbl,
                                                      float* __restrict__ ws, HP hp)
{
    int tid = blockIdx.x * 256 + threadIdx.x;
    float4* g4 = (float4*)ws;
    if (tid < 256) {                          // L0,L1 from M16 (nh=4)
        int q = tid & 3, r = (tid >> 2) & 3, p = (tid >> 4) & 3, b = tid >> 6;
        const float* M = ws + OFF_M16 + (size_t)b * 192;
        int o = p*16 + q*4 + r;
        float m0 = M[o], m1 = M[o + 64], m2 = M[o + 128];
        hash_store(tbl, g4, GOFF[0], 0, hp.n[0], m0, m1, m2, tid);
        hash_store(tbl, g4, GOFF[1], 1, hp.n[1], m0, m1, m2, tid);
    } else if (tid < 756) {                   // L2 from M12 (nh=5)
        int idx = tid - 256;
        int q = idx % 5; int t2 = idx / 5;
        int r = t2 % 5;  int t3 = t2 / 5;
        int p = t3 % 5;  int b = t3 / 5;
        const float* M = ws + OFF_M12 + (size_t)b * 375;
        int o = p*25 + q*5 + r;
        hash_store(tbl, g4, GOFF[2], 2, hp.n[2], M[o], M[o+125], M[o+250], idx);
    } else if (tid < 1620) {                  // L3 from M10 (nh=6)
        int idx = tid - 756;
        int q = idx % 6; int t2 = idx / 6;
        int r = t2 % 6;  int t3 = t2 / 6;
        int p = t3 % 6;  int b = t3 / 6;
        const float* M = ws + OFF_M10 + (size_t)b * 648;
        int o = p*36 + q*6 + r;
        hash_store(tbl, g4, GOFF[3], 3, hp.n[3], M[o], M[o+216], M[o+432], idx);
    } else if (tid < 3668) {                  // L4 from M8 (nh=8)
        int idx = tid - 1620;
        int q = idx & 7, r = (idx >> 3) & 7, p = (idx >> 6) & 7, b = idx >> 9;
        const float* M = ws + OFF_M8 + (size_t)b * 1536;
        int o = p*64 + q*8 + r;
        hash_store(tbl, g4, GOFF[4], 4, hp.n[4], M[o], M[o+512], M[o+1024], idx);
    } else if (tid < 7668) {                  // L5 from M6 (nh=10)
        int idx = tid - 3668;
        int q = idx % 10; int t2 = idx / 10;
        int r = t2 % 10;  int t3 = t2 / 10;
        int p = t3 % 10;  int b = t3 / 10;
        const float* M = ws + OFF_M6 + (size_t)b * 3000;
        int o = p*100 + q*10 + r;
        hash_store(tbl, g4, GOFF[5], 5, hp.n[5], M[o], M[o+1000], M[o+2000], idx);
    } else if (tid < 14580) {                 // L6 from M5 (nh=12)
        int idx = tid - 7668;
        int q = idx % 12; int t2 = idx / 12;
        int r = t2 % 12;  int t3 = t2 / 12;
        int p = t3 % 12;  int b = t3 / 12;
        const float* M = ws + OFF_M5 + (size_t)b * 5184;
        int o = p*144 + q*12 + r;
        hash_store(tbl, g4, GOFF[6], 6, hp.n[6], M[o], M[o+1728], M[o+3456], idx);
    } else if (tid < 30964) {                 // L7 from M4 (nh=16)
        int idx = tid - 14580;
        int q = idx & 15, r = (idx >> 4) & 15, p = (idx >> 8) & 15, b = idx >> 12;
        const float* M = ws + OFF_M4 + (size_t)b * 12288;
        int o = p*256 + q*16 + r;
        hash_store(tbl, g4, GOFF[7], 7, hp.n[7], M[o], M[o+4096], M[o+8192], idx);
    }
}

// ---------------- K4: output kernel ----------------
// one wave per output row (b,i,j); lane = k (fastest axis). Coalesced stores.
__global__ __launch_bounds__(256) void k_out(const float* __restrict__ x,
                                             const float* __restrict__ tbl,
                                             const float* __restrict__ ws,
                                             float* __restrict__ out, HP hp)
{
    __shared__ float4 tab[4][256];            // tables for levels 12..15
    int t = threadIdx.x;
    for (int v = t; v < 1024; v += 256) {
        const float* te = tbl + (size_t)(3072 + v) * 3;   // (12*256+v)*3
        tab[v >> 8][v & 255] = make_float4(te[0], te[1], te[2], 0.f);
    }
    __syncthreads();

    int row  = (blockIdx.x << 2) + (t >> 6);
    int lane = t & 63;
    int j = row & 63, i = (row >> 6) & 63, b = row >> 12;

    const float4* g4 = (const float4*)ws;
    float* op = out + (size_t)b * 12582912 + i * 4096 + j * 64 + lane;

    // ---- levels 12..15: identity resize, direct hash of x (h=i, w=lane, d=j)
    size_t xi = (size_t)b * 786432 + (size_t)i * 4096 + lane * 64 + j;
    float x0 = x[xi], x1 = x[xi + 262144], x2 = x[xi + 524288];
    #pragma unroll
    for (int u = 0; u < 4; ++u) {
        float nf = (float)hp.n[12 + u];
        u32 g0 = (u32)(x0 * nf);
        u32 g1 = ((u32)(x1 * nf)) * 2654435761u;
        u32 g2 = ((u32)(x2 * nf)) * 805459861u;
        float4 f = tab[u][(g0 ^ g1 ^ g2) & 255u];
        size_t c0 = (size_t)(36 + 3*u) * 262144;
        op[c0] = f.x; op[c0 + 262144] = f.y; op[c0 + 524288] = f.z;
    }

    // ---- levels 0..11: trilinear from feature grids [b][p][r][q]
    float fi = (float)i + 0.5f, fj = (float)j + 0.5f, fk = (float)lane + 0.5f;
    #pragma unroll 2
    for (int l = 0; l < 12; ++l) {
        const int nh = NH[l];
        const float iv = INVF[l];
        float pp = fminf(fmaxf(fi * iv - 0.5f, 0.f), (float)(nh - 1));
        float pr = fminf(fmaxf(fj * iv - 0.5f, 0.f), (float)(nh - 1));
        float pq = fminf(fmaxf(fk * iv - 0.5f, 0.f), (float)(nh - 1));
        int p0 = min((int)pp, nh - 2); float wp = pp - (float)p0;
        int r0 = min((int)pr, nh - 2); float wr = pr - (float)r0;
        int q0 = min((int)pq, nh - 2); float wq = pq - (float)q0;
        const float4* G = g4 + GOFF[l] + (size_t)b * nh * nh * nh;
        const float4* Ga = G + (p0 * nh + r0) * nh;
        const float4* Gb = Ga + nh;                 // r0+1
        const float4* Gc = G + ((p0 + 1) * nh + r0) * nh;
        const float4* Gd = Gc + nh;
        float4 a0 = Ga[q0], a1 = Ga[q0 + 1];
        float4 b0 = Gb[q0], b1 = Gb[q0 + 1];
        float4 c0_ = Gc[q0], c1 = Gc[q0 + 1];
        float4 d0 = Gd[q0], d1 = Gd[q0 + 1];
        // q-lerp, then r-lerp, then p-lerp (3 used components)
        float qa_x = lp(a0.x, a1.x, wq), qb_x = lp(b0.x, b1.x, wq);
        float qc_x = lp(c0_.x, c1.x, wq), qd_x = lp(d0.x, d1.x, wq);
        float qa_y = lp(a0.y, a1.y, wq), qb_y = lp(b0.y, b1.y, wq);
        float qc_y = lp(c0_.y, c1.y, wq), qd_y = lp(d0.y, d1.y, wq);
        float qa_z = lp(a0.z, a1.z, wq), qb_z = lp(b0.z, b1.z, wq);
        float qc_z = lp(c0_.z, c1.z, wq), qd_z = lp(d0.z, d1.z, wq);
        float rx0 = lp(qa_x, qb_x, wr), rx1 = lp(qc_x, qd_x, wr);
        float ry0 = lp(qa_y, qb_y, wr), ry1 = lp(qc_y, qd_y, wr);
        float rz0 = lp(qa_z, qb_z, wr), rz1 = lp(qc_z, qd_z, wr);
        float vx = lp(rx0, rx1, wp);
        float vy = lp(ry0, ry1, wp);
        float vz = lp(rz0, rz1, wp);
        size_t cc = (size_t)(3 * l) * 262144;
        op[cc] = vx; op[cc + 262144] = vy; op[cc + 524288] = vz;
    }
}

// ---------------- host ----------------
extern "C" void kernel_launch(void* const* d_in, const int* in_sizes, int n_in,
                              void* d_out, int out_size, void* d_ws, size_t ws_size,
                              hipStream_t stream)
{
    const float* x   = (const float*)d_in[0];
    const float* tbl = (const float*)d_in[1];
    float* out = (float*)d_out;
    float* ws  = (float*)d_ws;

    // levels computed with the same libm (exp/log/pow) as the Python reference,
    // so the n=63-vs-64 boundary at l=15 matches bit-for-bit.
    HP hp;
    double growth = std::exp(std::log(16.0) / 15.0);
    for (int l = 0; l < 16; ++l)
        hp.n[l] = (int)std::floor(4.0 * std::pow(growth, (double)l));

    hipLaunchKernelGGL(k_pool_base,    dim3(2052), dim3(256), 0, stream, x, ws);
    hipLaunchKernelGGL(k_pyr,          dim3(1128), dim3(256), 0, stream, tbl, ws, hp);
    hipLaunchKernelGGL(k_gather_small, dim3(121),  dim3(256), 0, stream, tbl, ws, hp);
    hipLaunchKernelGGL(k_out,          dim3(4096), dim3(256), 0, stream, x, tbl, ws, out, hp);
}

// Round 2
// 73.884 us; speedup vs baseline: 1.2736x; 1.2736x over previous
//
#include <hip/hip_runtime.h>
#include <cmath>
#include <cstdint>
#include <cstddef>

using u32 = unsigned int;

// ---------------- compile-time geometry ----------------
// levels n = [4,4,5,6,8,10,12,14,17,21,25,30,36,44,53,63/64]
// kh = 64//n = [16,16,12,10,8,6,5,4,3,3,2,2,1,1,1,1]
// grid res nh = 64//kh (levels 0..11; levels 12..15 are identity, nh=64)
constexpr int NH[12] = {4,4,5,6,8,10,12,16,21,21,32,32};

// float offsets of max-pool grids in ws  (layout [4][3][nh][nh][nh])
constexpr int OFF_M2  = 0;        // 32^3 *12 = 393216
constexpr int OFF_M3  = 393216;   // 21^3 *12 = 111132
constexpr int OFF_M5  = 504348;   // 12^3 *12 = 20736
constexpr int OFF_M4  = 525084;   // 16^3 *12 = 49152
constexpr int OFF_M6  = 574236;   // 10^3 *12 = 12000
constexpr int OFF_M8  = 586236;   //  8^3 *12 = 6144
constexpr int OFF_M10 = 592380;   //  6^3 *12 = 2592
constexpr int OFF_M12 = 594972;   //  5^3 *12 = 1500
constexpr int OFF_M16 = 596472;   //  4^3 *12 = 768  -> end 597240 (mult of 4)

// feature grids (float4), layout [b][p][r][q], offsets in float4 units
constexpr int GOFF[12] = {149310,149566,149822,150322,151186,153234,
                          157234,164146,180530,217574,254618,385690};
// total ws need: 516762 float4 = 8.27 MB

constexpr float invf_of(int nh){ return (float)(1.0/(64.0/(double)nh)); }
constexpr float INVF[12] = {invf_of(4),invf_of(4),invf_of(5),invf_of(6),
                            invf_of(8),invf_of(10),invf_of(12),invf_of(16),
                            invf_of(21),invf_of(21),invf_of(32),invf_of(32)};

struct HP { int n[16]; };

// ---------------- helpers ----------------
__device__ inline float lp(float a, float b, float w){ return fmaf(w, b - a, a); }

__device__ inline void hash_store(const float* __restrict__ tbl, float4* __restrict__ g4,
                                  int goff, int lvl, int n,
                                  float m0, float m1, float m2, int idx)
{
    float nf = (float)n;
    u32 g0 = (u32)(m0 * nf);
    u32 g1 = ((u32)(m1 * nf)) * 2654435761u;
    u32 g2 = ((u32)(m2 * nf)) * 805459861u;
    u32 h  = (g0 ^ g1 ^ g2) & 255u;
    const float* te = tbl + ((size_t)lvl * 256 + h) * 3;
    g4[goff + idx] = make_float4(te[0], te[1], te[2], 0.0f);
}

// ---------------- K1: base max-pools M2, M3, M5 from x ----------------
__global__ __launch_bounds__(256) void k_pool_base(const float* __restrict__ x,
                                                   float* __restrict__ ws)
{
    int tid = blockIdx.x * 256 + threadIdx.x;
    if (tid < 393216) {                       // M2: 2^3 windows
        int pd = tid & 31, pw = (tid >> 5) & 31, ph = (tid >> 10) & 31;
        int bc = tid >> 15;                   // [0,12)
        const float* xp = x + (size_t)bc * 262144 + (ph*2)*4096 + (pw*2)*64 + pd*2;
        float2 v00 = *(const float2*)(xp);
        float2 v01 = *(const float2*)(xp + 64);
        float2 v10 = *(const float2*)(xp + 4096);
        float2 v11 = *(const float2*)(xp + 4160);
        float m = fmaxf(fmaxf(fmaxf(v00.x,v00.y), fmaxf(v01.x,v01.y)),
                        fmaxf(fmaxf(v10.x,v10.y), fmaxf(v11.x,v11.y)));
        ws[OFF_M2 + tid] = m;
    } else if (tid < 504348) {                // M3: 3^3 windows
        int idx = tid - 393216;
        int pd = idx % 21; int t2 = idx / 21;
        int pw = t2 % 21;  int t3 = t2 / 21;
        int ph = t3 % 21;  int bc = t3 / 21;
        const float* xp = x + (size_t)bc * 262144 + (ph*3)*4096 + (pw*3)*64 + pd*3;
        float m = -1.f;
        #pragma unroll
        for (int dh = 0; dh < 3; ++dh)
        #pragma unroll
        for (int dw = 0; dw < 3; ++dw) {
            const float* r = xp + dh*4096 + dw*64;
            m = fmaxf(m, fmaxf(fmaxf(r[0], r[1]), r[2]));
        }
        ws[OFF_M3 + idx] = m;
    } else if (tid < 525084) {                // M5: 5^3 windows
        int idx = tid - 504348;
        int pd = idx % 12; int t2 = idx / 12;
        int pw = t2 % 12;  int t3 = t2 / 12;
        int ph = t3 % 12;  int bc = t3 / 12;
        const float* xp = x + (size_t)bc * 262144 + (ph*5)*4096 + (pw*5)*64 + pd*5;
        float m = -1.f;
        #pragma unroll
        for (int dh = 0; dh < 5; ++dh)
        #pragma unroll
        for (int dw = 0; dw < 5; ++dw) {
            const float* r = xp + dh*4096 + dw*64;
            m = fmaxf(m, fmaxf(fmaxf(fmaxf(r[0],r[1]), fmaxf(r[2],r[3])), r[4]));
        }
        ws[OFF_M5 + idx] = m;
    }
}

// ---------------- K2: pyramid grids + gathers for levels 8..11 ----------------
__global__ __launch_bounds__(256) void k_pyr(const float* __restrict__ tbl,
                                             float* __restrict__ ws, HP hp)
{
    int tid = blockIdx.x * 256 + threadIdx.x;
    float4* g4 = (float4*)ws;
    if (tid < 49152) {                        // M16: wave per cell, 8^3 over M2
        int w = tid >> 6, lane = tid & 63;
        int pd = w & 3, pw = (w >> 2) & 3, ph = (w >> 4) & 3, bc = w >> 6;
        const float* m2 = ws + OFF_M2 + (size_t)bc*32768 + (ph*8)*1024 + (pw*8)*32 + pd*8;
        float m = -1.f;
        #pragma unroll
        for (int e = 0; e < 8; ++e) {
            int id2 = (e << 6) | lane;        // 0..511
            int dd = id2 & 7, dw = (id2 >> 3) & 7, dh = id2 >> 6;
            m = fmaxf(m, m2[dh*1024 + dw*32 + dd]);
        }
        #pragma unroll
        for (int s = 32; s; s >>= 1) m = fmaxf(m, __shfl_xor(m, s, 64));
        if (lane == 0) ws[OFF_M16 + w] = m;
    } else if (tid < 98304) {                 // M4: 2^3 over M2
        int idx = tid - 49152;
        int pd = idx & 15, pw = (idx >> 4) & 15, ph = (idx >> 8) & 15, bc = idx >> 12;
        const float* m2 = ws + OFF_M2 + (size_t)bc*32768 + (ph*2)*1024 + (pw*2)*32 + pd*2;
        float2 u0 = *(const float2*)(m2);
        float2 u1 = *(const float2*)(m2 + 32);
        float2 u2 = *(const float2*)(m2 + 1024);
        float2 u3 = *(const float2*)(m2 + 1056);
        ws[OFF_M4 + idx] = fmaxf(fmaxf(fmaxf(u0.x,u0.y), fmaxf(u1.x,u1.y)),
                                 fmaxf(fmaxf(u2.x,u2.y), fmaxf(u3.x,u3.y)));
    } else if (tid < 110304) {                // M6: 3^3 over M2
        int idx = tid - 98304;
        int pd = idx % 10; int t2 = idx / 10;
        int pw = t2 % 10;  int t3 = t2 / 10;
        int ph = t3 % 10;  int bc = t3 / 10;
        const float* m2 = ws + OFF_M2 + (size_t)bc*32768 + (ph*3)*1024 + (pw*3)*32 + pd*3;
        float m = -1.f;
        #pragma unroll
        for (int dh = 0; dh < 3; ++dh)
        #pragma unroll
        for (int dw = 0; dw < 3; ++dw) {
            const float* r = m2 + dh*1024 + dw*32;
            m = fmaxf(m, fmaxf(fmaxf(r[0], r[1]), r[2]));
        }
        ws[OFF_M6 + idx] = m;
    } else if (tid < 116448) {                // M8: 4^3 over M2
        int idx = tid - 110304;
        int pd = idx & 7, pw = (idx >> 3) & 7, ph = (idx >> 6) & 7, bc = idx >> 9;
        const float* m2 = ws + OFF_M2 + (size_t)bc*32768 + (ph*4)*1024 + (pw*4)*32 + pd*4;
        float m = -1.f;
        #pragma unroll
        for (int dh = 0; dh < 4; ++dh)
        #pragma unroll
        for (int dw = 0; dw < 4; ++dw) {
            float4 v = *(const float4*)(m2 + dh*1024 + dw*32);
            m = fmaxf(m, fmaxf(fmaxf(v.x,v.y), fmaxf(v.z,v.w)));
        }
        ws[OFF_M8 + idx] = m;
    } else if (tid < 119040) {                // M10: 5^3 over M2
        int idx = tid - 116448;
        int pd = idx % 6; int t2 = idx / 6;
        int pw = t2 % 6;  int t3 = t2 / 6;
        int ph = t3 % 6;  int bc = t3 / 6;
        const float* m2 = ws + OFF_M2 + (size_t)bc*32768 + (ph*5)*1024 + (pw*5)*32 + pd*5;
        float m = -1.f;
        #pragma unroll
        for (int dh = 0; dh < 5; ++dh)
        #pragma unroll
        for (int dw = 0; dw < 5; ++dw) {
            const float* r = m2 + dh*1024 + dw*32;
            m = fmaxf(m, fmaxf(fmaxf(fmaxf(r[0],r[1]), fmaxf(r[2],r[3])), r[4]));
        }
        ws[OFF_M10 + idx] = m;
    } else if (tid < 120540) {                // M12: 4^3 over M3
        int idx = tid - 119040;
        int pd = idx % 5; int t2 = idx / 5;
        int pw = t2 % 5;  int t3 = t2 / 5;
        int ph = t3 % 5;  int bc = t3 / 5;
        const float* m3 = ws + OFF_M3 + (size_t)bc*9261 + (ph*4)*441 + (pw*4)*21 + pd*4;
        float m = -1.f;
        #pragma unroll
        for (int dh = 0; dh < 4; ++dh)
        #pragma unroll
        for (int dw = 0; dw < 4; ++dw) {
            const float* r = m3 + dh*441 + dw*21;
            m = fmaxf(m, fmaxf(fmaxf(r[0],r[1]), fmaxf(r[2],r[3])));
        }
        ws[OFF_M12 + idx] = m;
    } else if (tid < 251612) {                // gather L10,L11 from M2 (nh=32)
        int idx = tid - 120540;
        int q = idx & 31, r = (idx >> 5) & 31, p = (idx >> 10) & 31, b = idx >> 15;
        int o = (p << 10) + (q << 5) + r;     // M[b][c][p][q][r]
        const float* M = ws + OFF_M2 + (size_t)b * 98304;
        float m0 = M[o], m1 = M[o + 32768], m2 = M[o + 65536];
        hash_store(tbl, g4, GOFF[10], 10, hp.n[10], m0, m1, m2, idx);
        hash_store(tbl, g4, GOFF[11], 11, hp.n[11], m0, m1, m2, idx);
    } else if (tid < 288656) {                // gather L8,L9 from M3 (nh=21)
        int idx = tid - 251612;
        int q = idx % 21; int t2 = idx / 21;
        int r = t2 % 21;  int t3 = t2 / 21;
        int p = t3 % 21;  int b = t3 / 21;
        int o = p*441 + q*21 + r;
        const float* M = ws + OFF_M3 + (size_t)b * 27783;
        float m0 = M[o], m1 = M[o + 9261], m2 = M[o + 18522];
        hash_store(tbl, g4, GOFF[8], 8, hp.n[8], m0, m1, m2, idx);
        hash_store(tbl, g4, GOFF[9], 9, hp.n[9], m0, m1, m2, idx);
    }
}

// ---------------- K3: gathers for levels 0..7 ----------------
__global__ __launch_bounds__(256) void k_gather_small(const float* __restrict__ tbl,
                                                      float* __restrict__ ws, HP hp)
{
    int tid = blockIdx.x * 256 + threadIdx.x;
    float4* g4 = (float4*)ws;
    if (tid < 256) {                          // L0,L1 from M16 (nh=4)
        int q = tid & 3, r = (tid >> 2) & 3, p = (tid >> 4) & 3, b = tid >> 6;
        const float* M = ws + OFF_M16 + (size_t)b * 192;
        int o = p*16 + q*4 + r;
        float m0 = M[o], m1 = M[o + 64], m2 = M[o + 128];
        hash_store(tbl, g4, GOFF[0], 0, hp.n[0], m0, m1, m2, tid);
        hash_store(tbl, g4, GOFF[1], 1, hp.n[1], m0, m1, m2, tid);
    } else if (tid < 756) {                   // L2 from M12 (nh=5)
        int idx = tid - 256;
        int q = idx % 5; int t2 = idx / 5;
        int r = t2 % 5;  int t3 = t2 / 5;
        int p = t3 % 5;  int b = t3 / 5;
        const float* M = ws + OFF_M12 + (size_t)b * 375;
        int o = p*25 + q*5 + r;
        hash_store(tbl, g4, GOFF[2], 2, hp.n[2], M[o], M[o+125], M[o+250], idx);
    } else if (tid < 1620) {                  // L3 from M10 (nh=6)
        int idx = tid - 756;
        int q = idx % 6; int t2 = idx / 6;
        int r = t2 % 6;  int t3 = t2 / 6;
        int p = t3 % 6;  int b = t3 / 6;
        const float* M = ws + OFF_M10 + (size_t)b * 648;
        int o = p*36 + q*6 + r;
        hash_store(tbl, g4, GOFF[3], 3, hp.n[3], M[o], M[o+216], M[o+432], idx);
    } else if (tid < 3668) {                  // L4 from M8 (nh=8)
        int idx = tid - 1620;
        int q = idx & 7, r = (idx >> 3) & 7, p = (idx >> 6) & 7, b = idx >> 9;
        const float* M = ws + OFF_M8 + (size_t)b * 1536;
        int o = p*64 + q*8 + r;
        hash_store(tbl, g4, GOFF[4], 4, hp.n[4], M[o], M[o+512], M[o+1024], idx);
    } else if (tid < 7668) {                  // L5 from M6 (nh=10)
        int idx = tid - 3668;
        int q = idx % 10; int t2 = idx / 10;
        int r = t2 % 10;  int t3 = t2 / 10;
        int p = t3 % 10;  int b = t3 / 10;
        const float* M = ws + OFF_M6 + (size_t)b * 3000;
        int o = p*100 + q*10 + r;
        hash_store(tbl, g4, GOFF[5], 5, hp.n[5], M[o], M[o+1000], M[o+2000], idx);
    } else if (tid < 14580) {                 // L6 from M5 (nh=12)
        int idx = tid - 7668;
        int q = idx % 12; int t2 = idx / 12;
        int r = t2 % 12;  int t3 = t2 / 12;
        int p = t3 % 12;  int b = t3 / 12;
        const float* M = ws + OFF_M5 + (size_t)b * 5184;
        int o = p*144 + q*12 + r;
        hash_store(tbl, g4, GOFF[6], 6, hp.n[6], M[o], M[o+1728], M[o+3456], idx);
    } else if (tid < 30964) {                 // L7 from M4 (nh=16)
        int idx = tid - 14580;
        int q = idx & 15, r = (idx >> 4) & 15, p = (idx >> 8) & 15, b = idx >> 12;
        const float* M = ws + OFF_M4 + (size_t)b * 12288;
        int o = p*256 + q*16 + r;
        hash_store(tbl, g4, GOFF[7], 7, hp.n[7], M[o], M[o+4096], M[o+8192], idx);
    }
}

// ---------------- K4: output kernel (wave-cooperative trilinear) ----------------
// one wave per output row (b,i,j); lane = d (fastest axis). For a fixed row,
// p0/r0/wp/wr are wave-uniform; only q varies with lane. Lanes cooperatively
// load the 4 needed grid rows (coalesced), reduce them to a q-line with the
// r- and p-lerps, then each lane picks line[q0], line[q0+1] via __shfl.
__global__ __launch_bounds__(256) void k_out(const float* __restrict__ x,
                                             const float* __restrict__ tbl,
                                             const float* __restrict__ ws,
                                             float* __restrict__ out, HP hp)
{
    __shared__ float4 tab[4][256];            // tables for levels 12..15
    int t = threadIdx.x;
    for (int v = t; v < 1024; v += 256) {
        const float* te = tbl + (size_t)(3072 + v) * 3;   // (12*256+v)*3
        tab[v >> 8][v & 255] = make_float4(te[0], te[1], te[2], 0.f);
    }
    __syncthreads();

    int row  = (blockIdx.x << 2) + (t >> 6);
    int lane = t & 63;
    int j = row & 63, i = (row >> 6) & 63, b = row >> 12;

    const float4* g4 = (const float4*)ws;
    float* op = out + (size_t)b * 12582912 + i * 4096 + j * 64 + lane;

    // ---- levels 12..15: identity resize, direct hash of x (h=i, w=lane, d=j)
    size_t xi = (size_t)b * 786432 + (size_t)i * 4096 + lane * 64 + j;
    float x0 = x[xi], x1 = x[xi + 262144], x2 = x[xi + 524288];
    #pragma unroll
    for (int u = 0; u < 4; ++u) {
        float nf = (float)hp.n[12 + u];
        u32 g0 = (u32)(x0 * nf);
        u32 g1 = ((u32)(x1 * nf)) * 2654435761u;
        u32 g2 = ((u32)(x2 * nf)) * 805459861u;
        float4 f = tab[u][(g0 ^ g1 ^ g2) & 255u];
        size_t c0 = (size_t)(36 + 3*u) * 262144;
        __builtin_nontemporal_store(f.x, op + c0);
        __builtin_nontemporal_store(f.y, op + c0 + 262144);
        __builtin_nontemporal_store(f.z, op + c0 + 524288);
    }

    // ---- levels 0..11: trilinear from feature grids [b][p][r][q]
    float fi = (float)i + 0.5f, fj = (float)j + 0.5f, fk = (float)lane + 0.5f;
    #pragma unroll
    for (int l = 0; l < 12; ++l) {
        const int nh = NH[l];
        const float iv = INVF[l];
        float pp = fminf(fmaxf(fi * iv - 0.5f, 0.f), (float)(nh - 1));
        float pr = fminf(fmaxf(fj * iv - 0.5f, 0.f), (float)(nh - 1));
        float pq = fminf(fmaxf(fk * iv - 0.5f, 0.f), (float)(nh - 1));
        int p0 = min((int)pp, nh - 2); float wp = pp - (float)p0;
        int r0 = min((int)pr, nh - 2); float wr = pr - (float)r0;
        int q0 = min((int)pq, nh - 2); float wq = pq - (float)q0;
        const float4* G  = g4 + GOFF[l] + (size_t)b * (nh * nh * nh);
        const float4* Ga = G + (p0 * nh + r0) * nh;   // (p0,   r0  )
        const float4* Gb = Ga + nh;                   // (p0,   r0+1)
        const float4* Gc = Ga + nh * nh;              // (p0+1, r0  )
        const float4* Gd = Gc + nh;                   // (p0+1, r0+1)
        int cc = min(lane, nh - 1);                   // lanes >= nh: broadcast dup
        float4 a0 = Ga[cc], b0 = Gb[cc], c0v = Gc[cc], d0 = Gd[cc];
        // r-lerp then p-lerp -> q-line (valid in lanes 0..nh-1)
        float lx = lp(lp(a0.x, b0.x, wr), lp(c0v.x, d0.x, wr), wp);
        float ly = lp(lp(a0.y, b0.y, wr), lp(c0v.y, d0.y, wr), wp);
        float lz = lp(lp(a0.z, b0.z, wr), lp(c0v.z, d0.z, wr), wp);
        // q-lerp via cross-lane fetch of line[q0], line[q0+1]
        float vx = lp(__shfl(lx, q0, 64), __shfl(lx, q0 + 1, 64), wq);
        float vy = lp(__shfl(ly, q0, 64), __shfl(ly, q0 + 1, 64), wq);
        float vz = lp(__shfl(lz, q0, 64), __shfl(lz, q0 + 1, 64), wq);
        size_t ccs = (size_t)(3 * l) * 262144;
        __builtin_nontemporal_store(vx, op + ccs);
        __builtin_nontemporal_store(vy, op + ccs + 262144);
        __builtin_nontemporal_store(vz, op + ccs + 524288);
    }
}

// ---------------- host ----------------
extern "C" void kernel_launch(void* const* d_in, const int* in_sizes, int n_in,
                              void* d_out, int out_size, void* d_ws, size_t ws_size,
                              hipStream_t stream)
{
    const float* x   = (const float*)d_in[0];
    const float* tbl = (const float*)d_in[1];
    float* out = (float*)d_out;
    float* ws  = (float*)d_ws;

    // levels computed with the same libm (exp/log/pow) as the Python reference,
    // so the n=63-vs-64 boundary at l=15 matches bit-for-bit.
    HP hp;
    double growth = std::exp(std::log(16.0) / 15.0);
    for (int l = 0; l < 16; ++l)
        hp.n[l] = (int)std::floor(4.0 * std::pow(growth, (double)l));

    hipLaunchKernelGGL(k_pool_base,    dim3(2052), dim3(256), 0, stream, x, ws);
    hipLaunchKernelGGL(k_pyr,          dim3(1128), dim3(256), 0, stream, tbl, ws, hp);
    hipLaunchKernelGGL(k_gather_small, dim3(121),  dim3(256), 0, stream, tbl, ws, hp);
    hipLaunchKernelGGL(k_out,          dim3(4096), dim3(256), 0, stream, x, tbl, ws, out, hp);
}

// Round 4
// 65.719 us; speedup vs baseline: 1.4318x; 1.1242x over previous
//
#include <hip/hip_runtime.h>
#include <cmath>
#include <cstdint>
#include <cstddef>

using u32 = unsigned int;
typedef float f32x4 __attribute__((ext_vector_type(4)));

__device__ inline void nt_store4(float* p, float a, float b, float c, float d)
{
    f32x4 v; v.x = a; v.y = b; v.z = c; v.w = d;
    __builtin_nontemporal_store(v, (f32x4*)p);
}

// ---------------- compile-time geometry ----------------
// levels n = [4,4,5,6,8,10,12,14,17,21,25,30,36,44,53,63/64]
// kh = 64//n = [16,16,12,10,8,6,5,4,3,3,2,2,1,1,1,1]
// grid res nh = 64//kh (levels 0..11; levels 12..15 are identity, nh=64)
constexpr int NH[12] = {4,4,5,6,8,10,12,16,21,21,32,32};

// float offsets of max-pool grids in ws  (layout [4][3][nh][nh][nh])
constexpr int OFF_M2  = 0;        // 32^3 *12 = 393216
constexpr int OFF_M3  = 393216;   // 21^3 *12 = 111132
constexpr int OFF_M5  = 504348;   // 12^3 *12 = 20736
constexpr int OFF_M4  = 525084;   // 16^3 *12 = 49152
constexpr int OFF_M6  = 574236;   // 10^3 *12 = 12000
constexpr int OFF_M8  = 586236;   //  8^3 *12 = 6144
constexpr int OFF_M10 = 592380;   //  6^3 *12 = 2592
constexpr int OFF_M12 = 594972;   //  5^3 *12 = 1500
constexpr int OFF_M16 = 596472;   //  4^3 *12 = 768  -> end 597240 (mult of 4)

// feature grids (float4), layout [b][p][r][q], offsets in float4 units
constexpr int GOFF[12] = {149310,149566,149822,150322,151186,153234,
                          157234,164146,180530,217574,254618,385690};
// total ws need: 516762 float4 = 8.27 MB

constexpr float invf_of(int nh){ return (float)(1.0/(64.0/(double)nh)); }
constexpr float INVF[12] = {invf_of(4),invf_of(4),invf_of(5),invf_of(6),
                            invf_of(8),invf_of(10),invf_of(12),invf_of(16),
                            invf_of(21),invf_of(21),invf_of(32),invf_of(32)};

struct HP { int n[16]; };

// ---------------- helpers ----------------
__device__ inline float lp(float a, float b, float w){ return fmaf(w, b - a, a); }

__device__ inline void hash_store(const float* __restrict__ tbl, float4* __restrict__ g4,
                                  int goff, int lvl, int n,
                                  float m0, float m1, float m2, int idx)
{
    float nf = (float)n;
    u32 g0 = (u32)(m0 * nf);
    u32 g1 = ((u32)(m1 * nf)) * 2654435761u;
    u32 g2 = ((u32)(m2 * nf)) * 805459861u;
    u32 h  = (g0 ^ g1 ^ g2) & 255u;
    const float* te = tbl + ((size_t)lvl * 256 + h) * 3;
    g4[goff + idx] = make_float4(te[0], te[1], te[2], 0.0f);
}

// ---------------- K1: base max-pools M2, M3, M5 from x ----------------
__global__ __launch_bounds__(256) void k_pool_base(const float* __restrict__ x,
                                                   float* __restrict__ ws)
{
    int tid = blockIdx.x * 256 + threadIdx.x;
    if (tid < 393216) {                       // M2: 2^3 windows
        int pd = tid & 31, pw = (tid >> 5) & 31, ph = (tid >> 10) & 31;
        int bc = tid >> 15;                   // [0,12)
        const float* xp = x + (size_t)bc * 262144 + (ph*2)*4096 + (pw*2)*64 + pd*2;
        float2 v00 = *(const float2*)(xp);
        float2 v01 = *(const float2*)(xp + 64);
        float2 v10 = *(const float2*)(xp + 4096);
        float2 v11 = *(const float2*)(xp + 4160);
        float m = fmaxf(fmaxf(fmaxf(v00.x,v00.y), fmaxf(v01.x,v01.y)),
                        fmaxf(fmaxf(v10.x,v10.y), fmaxf(v11.x,v11.y)));
        ws[OFF_M2 + tid] = m;
    } else if (tid < 504348) {                // M3: 3^3 windows
        int idx = tid - 393216;
        int pd = idx % 21; int t2 = idx / 21;
        int pw = t2 % 21;  int t3 = t2 / 21;
        int ph = t3 % 21;  int bc = t3 / 21;
        const float* xp = x + (size_t)bc * 262144 + (ph*3)*4096 + (pw*3)*64 + pd*3;
        float m = -1.f;
        #pragma unroll
        for (int dh = 0; dh < 3; ++dh)
        #pragma unroll
        for (int dw = 0; dw < 3; ++dw) {
            const float* r = xp + dh*4096 + dw*64;
            m = fmaxf(m, fmaxf(fmaxf(r[0], r[1]), r[2]));
        }
        ws[OFF_M3 + idx] = m;
    } else if (tid < 525084) {                // M5: 5^3 windows
        int idx = tid - 504348;
        int pd = idx % 12; int t2 = idx / 12;
        int pw = t2 % 12;  int t3 = t2 / 12;
        int ph = t3 % 12;  int bc = t3 / 12;
        const float* xp = x + (size_t)bc * 262144 + (ph*5)*4096 + (pw*5)*64 + pd*5;
        float m = -1.f;
        #pragma unroll
        for (int dh = 0; dh < 5; ++dh)
        #pragma unroll
        for (int dw = 0; dw < 5; ++dw) {
            const float* r = xp + dh*4096 + dw*64;
            m = fmaxf(m, fmaxf(fmaxf(fmaxf(r[0],r[1]), fmaxf(r[2],r[3])), r[4]));
        }
        ws[OFF_M5 + idx] = m;
    }
}

// ---------------- K2: pyramid grids + gathers for levels 8..11 ----------------
__global__ __launch_bounds__(256) void k_pyr(const float* __restrict__ tbl,
                                             float* __restrict__ ws, HP hp)
{
    int tid = blockIdx.x * 256 + threadIdx.x;
    float4* g4 = (float4*)ws;
    if (tid < 49152) {                        // M16: wave per cell, 8^3 over M2
        int w = tid >> 6, lane = tid & 63;
        int pd = w & 3, pw = (w >> 2) & 3, ph = (w >> 4) & 3, bc = w >> 6;
        const float* m2 = ws + OFF_M2 + (size_t)bc*32768 + (ph*8)*1024 + (pw*8)*32 + pd*8;
        float m = -1.f;
        #pragma unroll
        for (int e = 0; e < 8; ++e) {
            int id2 = (e << 6) | lane;        // 0..511
            int dd = id2 & 7, dw = (id2 >> 3) & 7, dh = id2 >> 6;
            m = fmaxf(m, m2[dh*1024 + dw*32 + dd]);
        }
        #pragma unroll
        for (int s = 32; s; s >>= 1) m = fmaxf(m, __shfl_xor(m, s, 64));
        if (lane == 0) ws[OFF_M16 + w] = m;
    } else if (tid < 98304) {                 // M4: 2^3 over M2
        int idx = tid - 49152;
        int pd = idx & 15, pw = (idx >> 4) & 15, ph = (idx >> 8) & 15, bc = idx >> 12;
        const float* m2 = ws + OFF_M2 + (size_t)bc*32768 + (ph*2)*1024 + (pw*2)*32 + pd*2;
        float2 u0 = *(const float2*)(m2);
        float2 u1 = *(const float2*)(m2 + 32);
        float2 u2 = *(const float2*)(m2 + 1024);
        float2 u3 = *(const float2*)(m2 + 1056);
        ws[OFF_M4 + idx] = fmaxf(fmaxf(fmaxf(u0.x,u0.y), fmaxf(u1.x,u1.y)),
                                 fmaxf(fmaxf(u2.x,u2.y), fmaxf(u3.x,u3.y)));
    } else if (tid < 110304) {                // M6: 3^3 over M2
        int idx = tid - 98304;
        int pd = idx % 10; int t2 = idx / 10;
        int pw = t2 % 10;  int t3 = t2 / 10;
        int ph = t3 % 10;  int bc = t3 / 10;
        const float* m2 = ws + OFF_M2 + (size_t)bc*32768 + (ph*3)*1024 + (pw*3)*32 + pd*3;
        float m = -1.f;
        #pragma unroll
        for (int dh = 0; dh < 3; ++dh)
        #pragma unroll
        for (int dw = 0; dw < 3; ++dw) {
            const float* r = m2 + dh*1024 + dw*32;
            m = fmaxf(m, fmaxf(fmaxf(r[0], r[1]), r[2]));
        }
        ws[OFF_M6 + idx] = m;
    } else if (tid < 116448) {                // M8: 4^3 over M2
        int idx = tid - 110304;
        int pd = idx & 7, pw = (idx >> 3) & 7, ph = (idx >> 6) & 7, bc = idx >> 9;
        const float* m2 = ws + OFF_M2 + (size_t)bc*32768 + (ph*4)*1024 + (pw*4)*32 + pd*4;
        float m = -1.f;
        #pragma unroll
        for (int dh = 0; dh < 4; ++dh)
        #pragma unroll
        for (int dw = 0; dw < 4; ++dw) {
            float4 v = *(const float4*)(m2 + dh*1024 + dw*32);
            m = fmaxf(m, fmaxf(fmaxf(v.x,v.y), fmaxf(v.z,v.w)));
        }
        ws[OFF_M8 + idx] = m;
    } else if (tid < 119040) {                // M10: 5^3 over M2
        int idx = tid - 116448;
        int pd = idx % 6; int t2 = idx / 6;
        int pw = t2 % 6;  int t3 = t2 / 6;
        int ph = t3 % 6;  int bc = t3 / 6;
        const float* m2 = ws + OFF_M2 + (size_t)bc*32768 + (ph*5)*1024 + (pw*5)*32 + pd*5;
        float m = -1.f;
        #pragma unroll
        for (int dh = 0; dh < 5; ++dh)
        #pragma unroll
        for (int dw = 0; dw < 5; ++dw) {
            const float* r = m2 + dh*1024 + dw*32;
            m = fmaxf(m, fmaxf(fmaxf(fmaxf(r[0],r[1]), fmaxf(r[2],r[3])), r[4]));
        }
        ws[OFF_M10 + idx] = m;
    } else if (tid < 120540) {                // M12: 4^3 over M3
        int idx = tid - 119040;
        int pd = idx % 5; int t2 = idx / 5;
        int pw = t2 % 5;  int t3 = t2 / 5;
        int ph = t3 % 5;  int bc = t3 / 5;
        const float* m3 = ws + OFF_M3 + (size_t)bc*9261 + (ph*4)*441 + (pw*4)*21 + pd*4;
        float m = -1.f;
        #pragma unroll
        for (int dh = 0; dh < 4; ++dh)
        #pragma unroll
        for (int dw = 0; dw < 4; ++dw) {
            const float* r = m3 + dh*441 + dw*21;
            m = fmaxf(m, fmaxf(fmaxf(r[0],r[1]), fmaxf(r[2],r[3])));
        }
        ws[OFF_M12 + idx] = m;
    } else if (tid < 251612) {                // gather L10,L11 from M2 (nh=32)
        int idx = tid - 120540;
        int q = idx & 31, r = (idx >> 5) & 31, p = (idx >> 10) & 31, b = idx >> 15;
        int o = (p << 10) + (q << 5) + r;     // M[b][c][p][q][r]
        const float* M = ws + OFF_M2 + (size_t)b * 98304;
        float m0 = M[o], m1 = M[o + 32768], m2 = M[o + 65536];
        hash_store(tbl, g4, GOFF[10], 10, hp.n[10], m0, m1, m2, idx);
        hash_store(tbl, g4, GOFF[11], 11, hp.n[11], m0, m1, m2, idx);
    } else if (tid < 288656) {                // gather L8,L9 from M3 (nh=21)
        int idx = tid - 251612;
        int q = idx % 21; int t2 = idx / 21;
        int r = t2 % 21;  int t3 = t2 / 21;
        int p = t3 % 21;  int b = t3 / 21;
        int o = p*441 + q*21 + r;
        const float* M = ws + OFF_M3 + (size_t)b * 27783;
        float m0 = M[o], m1 = M[o + 9261], m2 = M[o + 18522];
        hash_store(tbl, g4, GOFF[8], 8, hp.n[8], m0, m1, m2, idx);
        hash_store(tbl, g4, GOFF[9], 9, hp.n[9], m0, m1, m2, idx);
    }
}

// ---------------- K3: gathers for levels 0..7 ----------------
__global__ __launch_bounds__(256) void k_gather_small(const float* __restrict__ tbl,
                                                      float* __restrict__ ws, HP hp)
{
    int tid = blockIdx.x * 256 + threadIdx.x;
    float4* g4 = (float4*)ws;
    if (tid < 256) {                          // L0,L1 from M16 (nh=4)
        int q = tid & 3, r = (tid >> 2) & 3, p = (tid >> 4) & 3, b = tid >> 6;
        const float* M = ws + OFF_M16 + (size_t)b * 192;
        int o = p*16 + q*4 + r;
        float m0 = M[o], m1 = M[o + 64], m2 = M[o + 128];
        hash_store(tbl, g4, GOFF[0], 0, hp.n[0], m0, m1, m2, tid);
        hash_store(tbl, g4, GOFF[1], 1, hp.n[1], m0, m1, m2, tid);
    } else if (tid < 756) {                   // L2 from M12 (nh=5)
        int idx = tid - 256;
        int q = idx % 5; int t2 = idx / 5;
        int r = t2 % 5;  int t3 = t2 / 5;
        int p = t3 % 5;  int b = t3 / 5;
        const float* M = ws + OFF_M12 + (size_t)b * 375;
        int o = p*25 + q*5 + r;
        hash_store(tbl, g4, GOFF[2], 2, hp.n[2], M[o], M[o+125], M[o+250], idx);
    } else if (tid < 1620) {                  // L3 from M10 (nh=6)
        int idx = tid - 756;
        int q = idx % 6; int t2 = idx / 6;
        int r = t2 % 6;  int t3 = t2 / 6;
        int p = t3 % 6;  int b = t3 / 6;
        const float* M = ws + OFF_M10 + (size_t)b * 648;
        int o = p*36 + q*6 + r;
        hash_store(tbl, g4, GOFF[3], 3, hp.n[3], M[o], M[o+216], M[o+432], idx);
    } else if (tid < 3668) {                  // L4 from M8 (nh=8)
        int idx = tid - 1620;
        int q = idx & 7, r = (idx >> 3) & 7, p = (idx >> 6) & 7, b = idx >> 9;
        const float* M = ws + OFF_M8 + (size_t)b * 1536;
        int o = p*64 + q*8 + r;
        hash_store(tbl, g4, GOFF[4], 4, hp.n[4], M[o], M[o+512], M[o+1024], idx);
    } else if (tid < 7668) {                  // L5 from M6 (nh=10)
        int idx = tid - 3668;
        int q = idx % 10; int t2 = idx / 10;
        int r = t2 % 10;  int t3 = t2 / 10;
        int p = t3 % 10;  int b = t3 / 10;
        const float* M = ws + OFF_M6 + (size_t)b * 3000;
        int o = p*100 + q*10 + r;
        hash_store(tbl, g4, GOFF[5], 5, hp.n[5], M[o], M[o+1000], M[o+2000], idx);
    } else if (tid < 14580) {                 // L6 from M5 (nh=12)
        int idx = tid - 7668;
        int q = idx % 12; int t2 = idx / 12;
        int r = t2 % 12;  int t3 = t2 / 12;
        int p = t3 % 12;  int b = t3 / 12;
        const float* M = ws + OFF_M5 + (size_t)b * 5184;
        int o = p*144 + q*12 + r;
        hash_store(tbl, g4, GOFF[6], 6, hp.n[6], M[o], M[o+1728], M[o+3456], idx);
    } else if (tid < 30964) {                 // L7 from M4 (nh=16)
        int idx = tid - 14580;
        int q = idx & 15, r = (idx >> 4) & 15, p = (idx >> 8) & 15, b = idx >> 12;
        const float* M = ws + OFF_M4 + (size_t)b * 12288;
        int o = p*256 + q*16 + r;
        hash_store(tbl, g4, GOFF[7], 7, hp.n[7], M[o], M[o+4096], M[o+8192], idx);
    }
}

// ---------------- K4a: identity levels 12..15 (LDS transpose, contiguous writes) --
// block = (b, i). out[b][36+3u+c][i][j][d] = tab[u][hash(x[b][:,i, w=d, dx=j])]
__global__ __launch_bounds__(512) void k_identity(const float* __restrict__ x,
                                                  const float* __restrict__ tbl,
                                                  float* __restrict__ out, HP hp)
{
    __shared__ float  xs[3 * 4160];           // [c][w][dx], pitch 65
    __shared__ float4 tab[1024];              // tables for levels 12..15
    const int t = threadIdx.x;
    const int b = blockIdx.x >> 6, i = blockIdx.x & 63;

    for (int v = t; v < 1024; v += 512) {
        const float* te = tbl + (size_t)(3072 + v) * 3;   // (12*256+v)*3
        tab[v] = make_float4(te[0], te[1], te[2], 0.f);
    }
    const float* xp = x + (size_t)b * 786432 + (size_t)i * 4096;
    #pragma unroll
    for (int c = 0; c < 3; ++c)
        for (int k = t; k < 4096; k += 512)
            xs[c * 4160 + (k >> 6) * 65 + (k & 63)] = xp[(size_t)c * 262144 + k];
    __syncthreads();

    float nfs[4] = {(float)hp.n[12], (float)hp.n[13],
                    (float)hp.n[14], (float)hp.n[15]};
    float* op = out + (size_t)b * 12582912 + (size_t)36 * 262144 + (size_t)i * 4096;

    #pragma unroll
    for (int it = 0; it < 2; ++it) {
        int pos = it * 512 + t;               // 0..1023
        int j = pos >> 4, d0 = (pos & 15) << 2;
        float xv[3][4];
        #pragma unroll
        for (int dd = 0; dd < 4; ++dd) {
            int wrow = (d0 + dd) * 65 + j;
            xv[0][dd] = xs[wrow];
            xv[1][dd] = xs[4160 + wrow];
            xv[2][dd] = xs[8320 + wrow];
        }
        #pragma unroll
        for (int u = 0; u < 4; ++u) {
            float4 f[4];
            #pragma unroll
            for (int dd = 0; dd < 4; ++dd) {
                u32 g0 = (u32)(xv[0][dd] * nfs[u]);
                u32 g1 = ((u32)(xv[1][dd] * nfs[u])) * 2654435761u;
                u32 g2 = ((u32)(xv[2][dd] * nfs[u])) * 805459861u;
                f[dd] = tab[(u << 8) | ((g0 ^ g1 ^ g2) & 255u)];
            }
            int off = u * 786432 + j * 64 + d0;    // u*3*262144
            nt_store4(op + off,          f[0].x, f[1].x, f[2].x, f[3].x);
            nt_store4(op + off + 262144, f[0].y, f[1].y, f[2].y, f[3].y);
            nt_store4(op + off + 524288, f[0].z, f[1].z, f[2].z, f[3].z);
        }
    }
}

// ---------------- K4b: interp levels 0..11 (LDS plane, contiguous writes) ----
// block = (level l, b, i). p0/wp block-uniform: stage p-lerped plane[r][q] in LDS,
// then sweep (j,d) with float4 stores per channel plane.
__global__ __launch_bounds__(256) void k_interp(const float* __restrict__ ws,
                                                float* __restrict__ out)
{
    __shared__ float4 plane[1024];            // [r][q], nh<=32
    const int t = threadIdx.x;
    const int l = blockIdx.y;
    const int b = blockIdx.x >> 6, i = blockIdx.x & 63;
    const int nh = NH[l];
    const float iv = INVF[l];
    const float4* g4 = (const float4*)ws;

    float fi = (float)i + 0.5f;
    float pp = fminf(fmaxf(fi * iv - 0.5f, 0.f), (float)(nh - 1));
    int p0 = min((int)pp, nh - 2);
    float wp = pp - (float)p0;
    const float4* Gp0 = g4 + GOFF[l] + (size_t)b * (nh * nh * nh) + p0 * nh * nh;
    const float4* Gp1 = Gp0 + nh * nh;
    for (int idx = t; idx < nh * nh; idx += 256) {
        float4 a = Gp0[idx], c = Gp1[idx];
        plane[idx] = make_float4(lp(a.x, c.x, wp), lp(a.y, c.y, wp),
                                 lp(a.z, c.z, wp), 0.f);
    }
    __syncthreads();

    float* op = out + (size_t)b * 12582912 + (size_t)(3 * l) * 262144 + (size_t)i * 4096;
    #pragma unroll
    for (int it = 0; it < 4; ++it) {
        int pos = it * 256 + t;               // 0..1023
        int j = pos >> 4, d0 = (pos & 15) << 2;
        float fj = (float)j + 0.5f;
        float pr = fminf(fmaxf(fj * iv - 0.5f, 0.f), (float)(nh - 1));
        int r0 = min((int)pr, nh - 2);
        float wr = pr - (float)r0;
        const float4* P0 = plane + r0 * nh;
        const float4* P1 = P0 + nh;
        float ox[4], oy[4], oz[4];
        #pragma unroll
        for (int dd = 0; dd < 4; ++dd) {
            float fk = (float)(d0 + dd) + 0.5f;
            float pq = fminf(fmaxf(fk * iv - 0.5f, 0.f), (float)(nh - 1));
            int q0 = min((int)pq, nh - 2);
            float wq = pq - (float)q0;
            float4 A = P0[q0], B = P0[q0 + 1];
            float4 C = P1[q0], D = P1[q0 + 1];
            float tx = lp(A.x, B.x, wq), bx = lp(C.x, D.x, wq);
            float ty = lp(A.y, B.y, wq), by = lp(C.y, D.y, wq);
            float tz = lp(A.z, B.z, wq), bz = lp(C.z, D.z, wq);
            ox[dd] = lp(tx, bx, wr);
            oy[dd] = lp(ty, by, wr);
            oz[dd] = lp(tz, bz, wr);
        }
        int off = j * 64 + d0;
        nt_store4(op + off,          ox[0], ox[1], ox[2], ox[3]);
        nt_store4(op + off + 262144, oy[0], oy[1], oy[2], oy[3]);
        nt_store4(op + off + 524288, oz[0], oz[1], oz[2], oz[3]);
    }
}

// ---------------- host ----------------
extern "C" void kernel_launch(void* const* d_in, const int* in_sizes, int n_in,
                              void* d_out, int out_size, void* d_ws, size_t ws_size,
                              hipStream_t stream)
{
    const float* x   = (const float*)d_in[0];
    const float* tbl = (const float*)d_in[1];
    float* out = (float*)d_out;
    float* ws  = (float*)d_ws;

    // levels computed with the same libm (exp/log/pow) as the Python reference,
    // so the n=63-vs-64 boundary at l=15 matches bit-for-bit.
    HP hp;
    double growth = std::exp(std::log(16.0) / 15.0);
    for (int l = 0; l < 16; ++l)
        hp.n[l] = (int)std::floor(4.0 * std::pow(growth, (double)l));

    hipLaunchKernelGGL(k_pool_base,    dim3(2052),     dim3(256), 0, stream, x, ws);
    hipLaunchKernelGGL(k_pyr,          dim3(1128),     dim3(256), 0, stream, tbl, ws, hp);
    hipLaunchKernelGGL(k_gather_small, dim3(121),      dim3(256), 0, stream, tbl, ws, hp);
    hipLaunchKernelGGL(k_identity,     dim3(256),      dim3(512), 0, stream, x, tbl, out, hp);
    hipLaunchKernelGGL(k_interp,       dim3(256, 12),  dim3(256), 0, stream, ws, out);
}

// Round 5
// 61.334 us; speedup vs baseline: 1.5342x; 1.0715x over previous
//
#include <hip/hip_runtime.h>
#include <cmath>
#include <cstdint>
#include <cstddef>

using u32 = unsigned int;
typedef float f32x4 __attribute__((ext_vector_type(4)));

__device__ inline void nt_store4(float* p, float a, float b, float c, float d)
{
    f32x4 v; v.x = a; v.y = b; v.z = c; v.w = d;
    __builtin_nontemporal_store(v, (f32x4*)p);
}

// ---------------- compile-time geometry ----------------
// levels n = [4,4,5,6,8,10,12,14,17,21,25,30,36,44,53,63/64]
// kh = 64//n = [16,16,12,10,8,6,5,4,3,3,2,2,1,1,1,1]
// grid res nh = 64//kh (levels 0..11; levels 12..15 are identity, nh=64)
constexpr int NH[12] = {4,4,5,6,8,10,12,16,21,21,32,32};

// float offsets of max-pool grids in ws  (layout [b][c][p(h)][w][d])
constexpr int OFF_M2  = 0;        // 32^3 *12 = 393216
constexpr int OFF_M3  = 393216;   // 21^3 *12 = 111132
constexpr int OFF_M5  = 504348;   // 12^3 *12 = 20736
constexpr int OFF_M4  = 525084;   // 16^3 *12 = 49152
constexpr int OFF_M6  = 574236;   // 10^3 *12 = 12000
constexpr int OFF_M8  = 586236;   //  8^3 *12 = 6144
constexpr int OFF_M10 = 592380;   //  6^3 *12 = 2592
constexpr int OFF_M12 = 594972;   //  5^3 *12 = 1500
constexpr int OFF_M16 = 596472;   //  4^3 *12 = 768  -> end 597240 floats (2.4 MB)

// pool source per interp level
constexpr int POFF[12] = {OFF_M16,OFF_M16,OFF_M12,OFF_M10,OFF_M8,OFF_M6,
                          OFF_M5, OFF_M4, OFF_M3, OFF_M3, OFF_M2, OFF_M2};

constexpr float invf_of(int nh){ return (float)(1.0/(64.0/(double)nh)); }
constexpr float INVF[12] = {invf_of(4),invf_of(4),invf_of(5),invf_of(6),
                            invf_of(8),invf_of(10),invf_of(12),invf_of(16),
                            invf_of(21),invf_of(21),invf_of(32),invf_of(32)};

struct HP { int n[16]; };

__device__ inline float lp(float a, float b, float w){ return fmaf(w, b - a, a); }

// ---------------- K1: base max-pools M2, M3, M5 from x ----------------
__global__ __launch_bounds__(256) void k_pool_base(const float* __restrict__ x,
                                                   float* __restrict__ ws)
{
    int tid = blockIdx.x * 256 + threadIdx.x;
    if (tid < 393216) {                       // M2: 2^3 windows
        int pd = tid & 31, pw = (tid >> 5) & 31, ph = (tid >> 10) & 31;
        int bc = tid >> 15;                   // [0,12)
        const float* xp = x + (size_t)bc * 262144 + (ph*2)*4096 + (pw*2)*64 + pd*2;
        float2 v00 = *(const float2*)(xp);
        float2 v01 = *(const float2*)(xp + 64);
        float2 v10 = *(const float2*)(xp + 4096);
        float2 v11 = *(const float2*)(xp + 4160);
        float m = fmaxf(fmaxf(fmaxf(v00.x,v00.y), fmaxf(v01.x,v01.y)),
                        fmaxf(fmaxf(v10.x,v10.y), fmaxf(v11.x,v11.y)));
        ws[OFF_M2 + tid] = m;
    } else if (tid < 504348) {                // M3: 3^3 windows
        int idx = tid - 393216;
        int pd = idx % 21; int t2 = idx / 21;
        int pw = t2 % 21;  int t3 = t2 / 21;
        int ph = t3 % 21;  int bc = t3 / 21;
        const float* xp = x + (size_t)bc * 262144 + (ph*3)*4096 + (pw*3)*64 + pd*3;
        float m = -1.f;
        #pragma unroll
        for (int dh = 0; dh < 3; ++dh)
        #pragma unroll
        for (int dw = 0; dw < 3; ++dw) {
            const float* r = xp + dh*4096 + dw*64;
            m = fmaxf(m, fmaxf(fmaxf(r[0], r[1]), r[2]));
        }
        ws[OFF_M3 + idx] = m;
    } else if (tid < 525084) {                // M5: 5^3 windows
        int idx = tid - 504348;
        int pd = idx % 12; int t2 = idx / 12;
        int pw = t2 % 12;  int t3 = t2 / 12;
        int ph = t3 % 12;  int bc = t3 / 12;
        const float* xp = x + (size_t)bc * 262144 + (ph*5)*4096 + (pw*5)*64 + pd*5;
        float m = -1.f;
        #pragma unroll
        for (int dh = 0; dh < 5; ++dh)
        #pragma unroll
        for (int dw = 0; dw < 5; ++dw) {
            const float* r = xp + dh*4096 + dw*64;
            m = fmaxf(m, fmaxf(fmaxf(fmaxf(r[0],r[1]), fmaxf(r[2],r[3])), r[4]));
        }
        ws[OFF_M5 + idx] = m;
    }
}

// ---------------- K2: pyramid pools from M2/M3 (no gathers) ----------------
// ranges: M16-wave [0,49152), M4 [49152,98304), M6 [98304,110304),
//         M8 [110304,116448), M10 [116448,119040), M12 [119040,120540)
__global__ __launch_bounds__(256) void k_pyr(float* __restrict__ ws)
{
    int tid = blockIdx.x * 256 + threadIdx.x;
    if (tid < 49152) {                        // M16: wave per cell, 8^3 over M2
        int w = tid >> 6, lane = tid & 63;
        int pd = w & 3, pw = (w >> 2) & 3, ph = (w >> 4) & 3, bc = w >> 6;
        const float* m2 = ws + OFF_M2 + (size_t)bc*32768 + (ph*8)*1024 + (pw*8)*32 + pd*8;
        float m = -1.f;
        #pragma unroll
        for (int e = 0; e < 8; ++e) {
            int id2 = (e << 6) | lane;        // 0..511
            int dd = id2 & 7, dw = (id2 >> 3) & 7, dh = id2 >> 6;
            m = fmaxf(m, m2[dh*1024 + dw*32 + dd]);
        }
        #pragma unroll
        for (int s = 32; s; s >>= 1) m = fmaxf(m, __shfl_xor(m, s, 64));
        if (lane == 0) ws[OFF_M16 + w] = m;
    } else if (tid < 98304) {                 // M4: 2^3 over M2
        int idx = tid - 49152;
        int pd = idx & 15, pw = (idx >> 4) & 15, ph = (idx >> 8) & 15, bc = idx >> 12;
        const float* m2 = ws + OFF_M2 + (size_t)bc*32768 + (ph*2)*1024 + (pw*2)*32 + pd*2;
        float2 u0 = *(const float2*)(m2);
        float2 u1 = *(const float2*)(m2 + 32);
        float2 u2 = *(const float2*)(m2 + 1024);
        float2 u3 = *(const float2*)(m2 + 1056);
        ws[OFF_M4 + idx] = fmaxf(fmaxf(fmaxf(u0.x,u0.y), fmaxf(u1.x,u1.y)),
                                 fmaxf(fmaxf(u2.x,u2.y), fmaxf(u3.x,u3.y)));
    } else if (tid < 110304) {                // M6: 3^3 over M2
        int idx = tid - 98304;
        int pd = idx % 10; int t2 = idx / 10;
        int pw = t2 % 10;  int t3 = t2 / 10;
        int ph = t3 % 10;  int bc = t3 / 10;
        const float* m2 = ws + OFF_M2 + (size_t)bc*32768 + (ph*3)*1024 + (pw*3)*32 + pd*3;
        float m = -1.f;
        #pragma unroll
        for (int dh = 0; dh < 3; ++dh)
        #pragma unroll
        for (int dw = 0; dw < 3; ++dw) {
            const float* r = m2 + dh*1024 + dw*32;
            m = fmaxf(m, fmaxf(fmaxf(r[0], r[1]), r[2]));
        }
        ws[OFF_M6 + idx] = m;
    } else if (tid < 116448) {                // M8: 4^3 over M2
        int idx = tid - 110304;
        int pd = idx & 7, pw = (idx >> 3) & 7, ph = (idx >> 6) & 7, bc = idx >> 9;
        const float* m2 = ws + OFF_M2 + (size_t)bc*32768 + (ph*4)*1024 + (pw*4)*32 + pd*4;
        float m = -1.f;
        #pragma unroll
        for (int dh = 0; dh < 4; ++dh)
        #pragma unroll
        for (int dw = 0; dw < 4; ++dw) {
            float4 v = *(const float4*)(m2 + dh*1024 + dw*32);
            m = fmaxf(m, fmaxf(fmaxf(v.x,v.y), fmaxf(v.z,v.w)));
        }
        ws[OFF_M8 + idx] = m;
    } else if (tid < 119040) {                // M10: 5^3 over M2
        int idx = tid - 116448;
        int pd = idx % 6; int t2 = idx / 6;
        int pw = t2 % 6;  int t3 = t2 / 6;
        int ph = t3 % 6;  int bc = t3 / 6;
        const float* m2 = ws + OFF_M2 + (size_t)bc*32768 + (ph*5)*1024 + (pw*5)*32 + pd*5;
        float m = -1.f;
        #pragma unroll
        for (int dh = 0; dh < 5; ++dh)
        #pragma unroll
        for (int dw = 0; dw < 5; ++dw) {
            const float* r = m2 + dh*1024 + dw*32;
            m = fmaxf(m, fmaxf(fmaxf(fmaxf(r[0],r[1]), fmaxf(r[2],r[3])), r[4]));
        }
        ws[OFF_M10 + idx] = m;
    } else if (tid < 120540) {                // M12: 4^3 over M3
        int idx = tid - 119040;
        int pd = idx % 5; int t2 = idx / 5;
        int pw = t2 % 5;  int t3 = t2 / 5;
        int ph = t3 % 5;  int bc = t3 / 5;
        const float* m3 = ws + OFF_M3 + (size_t)bc*9261 + (ph*4)*441 + (pw*4)*21 + pd*4;
        float m = -1.f;
        #pragma unroll
        for (int dh = 0; dh < 4; ++dh)
        #pragma unroll
        for (int dw = 0; dw < 4; ++dw) {
            const float* r = m3 + dh*441 + dw*21;
            m = fmaxf(m, fmaxf(fmaxf(r[0],r[1]), fmaxf(r[2],r[3])));
        }
        ws[OFF_M12 + idx] = m;
    }
}

// ---------------- K3: identity levels 12..15 (LDS transpose, 512 blocks) ----
// block = (b, i, j-half). out[b][36+3u+c][i][j][d] = tab[u][hash(x[b][:, i, w=d, dx=j])]
__global__ __launch_bounds__(256) void k_identity(const float* __restrict__ x,
                                                  const float* __restrict__ tbl,
                                                  float* __restrict__ out, HP hp)
{
    __shared__ float  xs[3 * 2112];           // [c][w][jl], pitch 33 (64*33=2112)
    __shared__ float4 tab[1024];              // tables for levels 12..15
    const int t = threadIdx.x;
    const int b = blockIdx.x >> 7;
    const int i = (blockIdx.x >> 1) & 63;
    const int jh = blockIdx.x & 1;            // j-half (32 j's)

    for (int v = t; v < 1024; v += 256) {
        const float* te = tbl + (size_t)(3072 + v) * 3;   // (12*256+v)*3
        tab[v] = make_float4(te[0], te[1], te[2], 0.f);
    }
    const float* xp = x + (size_t)b * 786432 + (size_t)i * 4096 + jh * 32;
    #pragma unroll
    for (int c = 0; c < 3; ++c)
        for (int k = t; k < 2048; k += 256) {
            int w = k >> 5, jl = k & 31;
            xs[c * 2112 + w * 33 + jl] = xp[(size_t)c * 262144 + w * 64 + jl];
        }
    __syncthreads();

    float nfs[4] = {(float)hp.n[12], (float)hp.n[13],
                    (float)hp.n[14], (float)hp.n[15]};
    float* op = out + (size_t)b * 12582912 + (size_t)36 * 262144
                    + (size_t)i * 4096 + jh * 2048;   // jh*32*64

    #pragma unroll
    for (int it = 0; it < 2; ++it) {
        int pos = it * 256 + t;               // 0..511
        int jl = pos >> 4, d0 = (pos & 15) << 2;
        float xv[3][4];
        #pragma unroll
        for (int dd = 0; dd < 4; ++dd) {
            int wrow = (d0 + dd) * 33 + jl;
            xv[0][dd] = xs[wrow];
            xv[1][dd] = xs[2112 + wrow];
            xv[2][dd] = xs[4224 + wrow];
        }
        #pragma unroll
        for (int u = 0; u < 4; ++u) {
            float4 f[4];
            #pragma unroll
            for (int dd = 0; dd < 4; ++dd) {
                u32 g0 = (u32)(xv[0][dd] * nfs[u]);
                u32 g1 = ((u32)(xv[1][dd] * nfs[u])) * 2654435761u;
                u32 g2 = ((u32)(xv[2][dd] * nfs[u])) * 805459861u;
                f[dd] = tab[(u << 8) | ((g0 ^ g1 ^ g2) & 255u)];
            }
            int off = u * 786432 + jl * 64 + d0;    // u*3*262144
            nt_store4(op + off,          f[0].x, f[1].x, f[2].x, f[3].x);
            nt_store4(op + off + 262144, f[0].y, f[1].y, f[2].y, f[3].y);
            nt_store4(op + off + 524288, f[0].z, f[1].z, f[2].z, f[3].z);
        }
    }
}

// ---------------- K4: interp levels 0..11 (hash fused into plane staging) ----
// block = (level l, b, i). p0/wp block-uniform: hash the two needed pool
// planes, p-lerp features into LDS plane[r(d-grid)][q(w-grid)], then sweep
// (j,d) with float4 stores per channel plane.
__global__ __launch_bounds__(256) void k_interp(const float* __restrict__ ws,
                                                const float* __restrict__ tbl,
                                                float* __restrict__ out, HP hp)
{
    __shared__ float4 plane[1056];            // [r][q], pitch nh+1, max 32*33
    const int t = threadIdx.x;
    const int l = blockIdx.y;
    const int b = blockIdx.x >> 6, i = blockIdx.x & 63;
    const int nh = NH[l];
    const int pitch = nh + 1;
    const float iv = INVF[l];
    const float nf = (float)hp.n[l];

    float fi = (float)i + 0.5f;
    float pp = fminf(fmaxf(fi * iv - 0.5f, 0.f), (float)(nh - 1));
    int p0 = min((int)pp, nh - 2);
    float wp = pp - (float)p0;

    const int nsq = nh * nh, ncb = nsq * nh;
    const float* M   = ws + POFF[l] + (size_t)b * 3 * ncb;   // [c][p][w][d]
    const float* Mp0 = M + p0 * nsq;
    const float* Mp1 = Mp0 + nsq;
    const float* tl  = tbl + (size_t)l * 768;                // level table (256*3)

    for (int idx = t; idx < nsq; idx += 256) {
        int w = idx / nh, d = idx - w * nh;
        float a0 = Mp0[idx], a1 = Mp0[idx + ncb], a2 = Mp0[idx + 2*ncb];
        u32 h0 = ((u32)(a0*nf) ^ (((u32)(a1*nf))*2654435761u)
                               ^ (((u32)(a2*nf))*805459861u)) & 255u;
        const float* t0 = tl + h0 * 3;
        float b0 = Mp1[idx], b1 = Mp1[idx + ncb], b2 = Mp1[idx + 2*ncb];
        u32 h1 = ((u32)(b0*nf) ^ (((u32)(b1*nf))*2654435761u)
                               ^ (((u32)(b2*nf))*805459861u)) & 255u;
        const float* t1 = tl + h1 * 3;
        plane[d * pitch + w] = make_float4(lp(t0[0], t1[0], wp),
                                           lp(t0[1], t1[1], wp),
                                           lp(t0[2], t1[2], wp), 0.f);
    }
    __syncthreads();

    float* op = out + (size_t)b * 12582912 + (size_t)(3 * l) * 262144 + (size_t)i * 4096;
    #pragma unroll
    for (int it = 0; it < 4; ++it) {
        int pos = it * 256 + t;               // 0..1023
        int j = pos >> 4, d0 = (pos & 15) << 2;
        float fj = (float)j + 0.5f;
        float pr = fminf(fmaxf(fj * iv - 0.5f, 0.f), (float)(nh - 1));
        int r0 = min((int)pr, nh - 2);
        float wr = pr - (float)r0;
        const float4* P0 = plane + r0 * pitch;
        const float4* P1 = P0 + pitch;
        float ox[4], oy[4], oz[4];
        #pragma unroll
        for (int dd = 0; dd < 4; ++dd) {
            float fk = (float)(d0 + dd) + 0.5f;
            float pq = fminf(fmaxf(fk * iv - 0.5f, 0.f), (float)(nh - 1));
            int q0 = min((int)pq, nh - 2);
            float wq = pq - (float)q0;
            float4 A = P0[q0], B = P0[q0 + 1];
            float4 C = P1[q0], D = P1[q0 + 1];
            float tx = lp(A.x, B.x, wq), bx = lp(C.x, D.x, wq);
            float ty = lp(A.y, B.y, wq), by = lp(C.y, D.y, wq);
            float tz = lp(A.z, B.z, wq), bz = lp(C.z, D.z, wq);
            ox[dd] = lp(tx, bx, wr);
            oy[dd] = lp(ty, by, wr);
            oz[dd] = lp(tz, bz, wr);
        }
        int off = j * 64 + d0;
        nt_store4(op + off,          ox[0], ox[1], ox[2], ox[3]);
        nt_store4(op + off + 262144, oy[0], oy[1], oy[2], oy[3]);
        nt_store4(op + off + 524288, oz[0], oz[1], oz[2], oz[3]);
    }
}

// ---------------- host ----------------
extern "C" void kernel_launch(void* const* d_in, const int* in_sizes, int n_in,
                              void* d_out, int out_size, void* d_ws, size_t ws_size,
                              hipStream_t stream)
{
    const float* x   = (const float*)d_in[0];
    const float* tbl = (const float*)d_in[1];
    float* out = (float*)d_out;
    float* ws  = (float*)d_ws;

    // levels computed with the same libm (exp/log/pow) as the Python reference,
    // so the n=63-vs-64 boundary at l=15 matches bit-for-bit.
    HP hp;
    double growth = std::exp(std::log(16.0) / 15.0);
    for (int l = 0; l < 16; ++l)
        hp.n[l] = (int)std::floor(4.0 * std::pow(growth, (double)l));

    hipLaunchKernelGGL(k_pool_base, dim3(2052),    dim3(256), 0, stream, x, ws);
    hipLaunchKernelGGL(k_pyr,       dim3(471),     dim3(256), 0, stream, ws);
    hipLaunchKernelGGL(k_identity,  dim3(512),     dim3(256), 0, stream, x, tbl, out, hp);
    hipLaunchKernelGGL(k_interp,    dim3(256, 12), dim3(256), 0, stream, ws, tbl, out, hp);
}

// Round 6
// 53.696 us; speedup vs baseline: 1.7524x; 1.1423x over previous
//
#include <hip/hip_runtime.h>
#include <cmath>
#include <cstdint>
#include <cstddef>

using u32 = unsigned int;
typedef float f32x4 __attribute__((ext_vector_type(4)));

// plain (cacheable) vector store — out working set fits LLC; dirty lines stay
// resident across graph replays, so avoid nontemporal/no-allocate hints.
__device__ inline void st4(float* p, float a, float b, float c, float d)
{
    f32x4 v; v.x = a; v.y = b; v.z = c; v.w = d;
    *(f32x4*)p = v;
}

// ---------------- compile-time geometry ----------------
// levels n = [4,4,5,6,8,10,12,14,17,21,25,30,36,44,53,63/64]
// kh = 64//n = [16,16,12,10,8,6,5,4,3,3,2,2,1,1,1,1]
// grid res nh = 64//kh (levels 0..11; levels 12..15 are identity, nh=64)
constexpr int NH[12] = {4,4,5,6,8,10,12,16,21,21,32,32};

// float offsets of max-pool grids in ws  (layout [b][c][p(h)][w][d])
constexpr int OFF_M2  = 0;        // 32^3 *12 = 393216
constexpr int OFF_M3  = 393216;   // 21^3 *12 = 111132
constexpr int OFF_M5  = 504348;   // 12^3 *12 = 20736
constexpr int OFF_M4  = 525084;   // 16^3 *12 = 49152
constexpr int OFF_M6  = 574236;   // 10^3 *12 = 12000
constexpr int OFF_M8  = 586236;   //  8^3 *12 = 6144
constexpr int OFF_M10 = 592380;   //  6^3 *12 = 2592
constexpr int OFF_M12 = 594972;   //  5^3 *12 = 1500
constexpr int OFF_M16 = 596472;   //  4^3 *12 = 768  -> end 597240 floats (2.4 MB)

// pool source per interp level
constexpr int POFF[12] = {OFF_M16,OFF_M16,OFF_M12,OFF_M10,OFF_M8,OFF_M6,
                          OFF_M5, OFF_M4, OFF_M3, OFF_M3, OFF_M2, OFF_M2};

constexpr float invf_of(int nh){ return (float)(1.0/(64.0/(double)nh)); }
constexpr float INVF[12] = {invf_of(4),invf_of(4),invf_of(5),invf_of(6),
                            invf_of(8),invf_of(10),invf_of(12),invf_of(16),
                            invf_of(21),invf_of(21),invf_of(32),invf_of(32)};

struct HP { int n[16]; };

__device__ inline float lp(float a, float b, float w){ return fmaf(w, b - a, a); }

// ---------------- K1: base max-pools M2, M3, M5 from x ----------------
__global__ __launch_bounds__(256) void k_pool_base(const float* __restrict__ x,
                                                   float* __restrict__ ws)
{
    int tid = blockIdx.x * 256 + threadIdx.x;
    if (tid < 393216) {                       // M2: 2^3 windows
        int pd = tid & 31, pw = (tid >> 5) & 31, ph = (tid >> 10) & 31;
        int bc = tid >> 15;                   // [0,12)
        const float* xp = x + (size_t)bc * 262144 + (ph*2)*4096 + (pw*2)*64 + pd*2;
        float2 v00 = *(const float2*)(xp);
        float2 v01 = *(const float2*)(xp + 64);
        float2 v10 = *(const float2*)(xp + 4096);
        float2 v11 = *(const float2*)(xp + 4160);
        float m = fmaxf(fmaxf(fmaxf(v00.x,v00.y), fmaxf(v01.x,v01.y)),
                        fmaxf(fmaxf(v10.x,v10.y), fmaxf(v11.x,v11.y)));
        ws[OFF_M2 + tid] = m;
    } else if (tid < 504348) {                // M3: 3^3 windows
        int idx = tid - 393216;
        int pd = idx % 21; int t2 = idx / 21;
        int pw = t2 % 21;  int t3 = t2 / 21;
        int ph = t3 % 21;  int bc = t3 / 21;
        const float* xp = x + (size_t)bc * 262144 + (ph*3)*4096 + (pw*3)*64 + pd*3;
        float m = -1.f;
        #pragma unroll
        for (int dh = 0; dh < 3; ++dh)
        #pragma unroll
        for (int dw = 0; dw < 3; ++dw) {
            const float* r = xp + dh*4096 + dw*64;
            m = fmaxf(m, fmaxf(fmaxf(r[0], r[1]), r[2]));
        }
        ws[OFF_M3 + idx] = m;
    } else if (tid < 525084) {                // M5: 5^3 windows
        int idx = tid - 504348;
        int pd = idx % 12; int t2 = idx / 12;
        int pw = t2 % 12;  int t3 = t2 / 12;
        int ph = t3 % 12;  int bc = t3 / 12;
        const float* xp = x + (size_t)bc * 262144 + (ph*5)*4096 + (pw*5)*64 + pd*5;
        float m = -1.f;
        #pragma unroll
        for (int dh = 0; dh < 5; ++dh)
        #pragma unroll
        for (int dw = 0; dw < 5; ++dw) {
            const float* r = xp + dh*4096 + dw*64;
            m = fmaxf(m, fmaxf(fmaxf(fmaxf(r[0],r[1]), fmaxf(r[2],r[3])), r[4]));
        }
        ws[OFF_M5 + idx] = m;
    }
}

// ---------------- K2: pyramid pools from M2/M3 ----------------
__global__ __launch_bounds__(256) void k_pyr(float* __restrict__ ws)
{
    int tid = blockIdx.x * 256 + threadIdx.x;
    if (tid < 49152) {                        // M16: wave per cell, 8^3 over M2
        int w = tid >> 6, lane = tid & 63;
        int pd = w & 3, pw = (w >> 2) & 3, ph = (w >> 4) & 3, bc = w >> 6;
        const float* m2 = ws + OFF_M2 + (size_t)bc*32768 + (ph*8)*1024 + (pw*8)*32 + pd*8;
        float m = -1.f;
        #pragma unroll
        for (int e = 0; e < 8; ++e) {
            int id2 = (e << 6) | lane;        // 0..511
            int dd = id2 & 7, dw = (id2 >> 3) & 7, dh = id2 >> 6;
            m = fmaxf(m, m2[dh*1024 + dw*32 + dd]);
        }
        #pragma unroll
        for (int s = 32; s; s >>= 1) m = fmaxf(m, __shfl_xor(m, s, 64));
        if (lane == 0) ws[OFF_M16 + w] = m;
    } else if (tid < 98304) {                 // M4: 2^3 over M2
        int idx = tid - 49152;
        int pd = idx & 15, pw = (idx >> 4) & 15, ph = (idx >> 8) & 15, bc = idx >> 12;
        const float* m2 = ws + OFF_M2 + (size_t)bc*32768 + (ph*2)*1024 + (pw*2)*32 + pd*2;
        float2 u0 = *(const float2*)(m2);
        float2 u1 = *(const float2*)(m2 + 32);
        float2 u2 = *(const float2*)(m2 + 1024);
        float2 u3 = *(const float2*)(m2 + 1056);
        ws[OFF_M4 + idx] = fmaxf(fmaxf(fmaxf(u0.x,u0.y), fmaxf(u1.x,u1.y)),
                                 fmaxf(fmaxf(u2.x,u2.y), fmaxf(u3.x,u3.y)));
    } else if (tid < 110304) {                // M6: 3^3 over M2
        int idx = tid - 98304;
        int pd = idx % 10; int t2 = idx / 10;
        int pw = t2 % 10;  int t3 = t2 / 10;
        int ph = t3 % 10;  int bc = t3 / 10;
        const float* m2 = ws + OFF_M2 + (size_t)bc*32768 + (ph*3)*1024 + (pw*3)*32 + pd*3;
        float m = -1.f;
        #pragma unroll
        for (int dh = 0; dh < 3; ++dh)
        #pragma unroll
        for (int dw = 0; dw < 3; ++dw) {
            const float* r = m2 + dh*1024 + dw*32;
            m = fmaxf(m, fmaxf(fmaxf(r[0], r[1]), r[2]));
        }
        ws[OFF_M6 + idx] = m;
    } else if (tid < 116448) {                // M8: 4^3 over M2
        int idx = tid - 110304;
        int pd = idx & 7, pw = (idx >> 3) & 7, ph = (idx >> 6) & 7, bc = idx >> 9;
        const float* m2 = ws + OFF_M2 + (size_t)bc*32768 + (ph*4)*1024 + (pw*4)*32 + pd*4;
        float m = -1.f;
        #pragma unroll
        for (int dh = 0; dh < 4; ++dh)
        #pragma unroll
        for (int dw = 0; dw < 4; ++dw) {
            float4 v = *(const float4*)(m2 + dh*1024 + dw*32);
            m = fmaxf(m, fmaxf(fmaxf(v.x,v.y), fmaxf(v.z,v.w)));
        }
        ws[OFF_M8 + idx] = m;
    } else if (tid < 119040) {                // M10: 5^3 over M2
        int idx = tid - 116448;
        int pd = idx % 6; int t2 = idx / 6;
        int pw = t2 % 6;  int t3 = t2 / 6;
        int ph = t3 % 6;  int bc = t3 / 6;
        const float* m2 = ws + OFF_M2 + (size_t)bc*32768 + (ph*5)*1024 + (pw*5)*32 + pd*5;
        float m = -1.f;
        #pragma unroll
        for (int dh = 0; dh < 5; ++dh)
        #pragma unroll
        for (int dw = 0; dw < 5; ++dw) {
            const float* r = m2 + dh*1024 + dw*32;
            m = fmaxf(m, fmaxf(fmaxf(fmaxf(r[0],r[1]), fmaxf(r[2],r[3])), r[4]));
        }
        ws[OFF_M10 + idx] = m;
    } else if (tid < 120540) {                // M12: 4^3 over M3
        int idx = tid - 119040;
        int pd = idx % 5; int t2 = idx / 5;
        int pw = t2 % 5;  int t3 = t2 / 5;
        int ph = t3 % 5;  int bc = t3 / 5;
        const float* m3 = ws + OFF_M3 + (size_t)bc*9261 + (ph*4)*441 + (pw*4)*21 + pd*4;
        float m = -1.f;
        #pragma unroll
        for (int dh = 0; dh < 4; ++dh)
        #pragma unroll
        for (int dw = 0; dw < 4; ++dw) {
            const float* r = m3 + dh*441 + dw*21;
            m = fmaxf(m, fmaxf(fmaxf(r[0],r[1]), fmaxf(r[2],r[3])));
        }
        ws[OFF_M12 + idx] = m;
    }
}

// ---------------- K3: uber output kernel ----------------
// grid (256, 14): y = 0..11 -> interp level y, block x = (b,i)
//                 y = 12,13 -> identity levels 12..15, j-half = y-12
// Shared buffer union: interp uses plane[1056] f4 (16.9 KB);
// identity uses tab[1024] f4 + xs[3*2112] floats (41.7 KB total).
__global__ __launch_bounds__(256) void k_out(const float* __restrict__ x,
                                             const float* __restrict__ ws,
                                             const float* __restrict__ tbl,
                                             float* __restrict__ out, HP hp)
{
    __shared__ float4 shb[2608];
    const int t = threadIdx.x;
    const int l = blockIdx.y;
    const int b = blockIdx.x >> 6, i = blockIdx.x & 63;

    if (l < 12) {
        // ---- trilinear interp level l, hash fused into plane staging ----
        float4* plane = shb;                  // [r(d-grid row)][q(w-grid col)]
        const int nh = NH[l];
        const int pitch = nh + 1;
        const float iv = INVF[l];
        const float nf = (float)hp.n[l];

        float fi = (float)i + 0.5f;
        float pp = fminf(fmaxf(fi * iv - 0.5f, 0.f), (float)(nh - 1));
        int p0 = min((int)pp, nh - 2);
        float wp = pp - (float)p0;

        const int nsq = nh * nh, ncb = nsq * nh;
        const float* M   = ws + POFF[l] + (size_t)b * 3 * ncb;   // [c][p][w][d]
        const float* Mp0 = M + p0 * nsq;
        const float* Mp1 = Mp0 + nsq;
        const float* tl  = tbl + (size_t)l * 768;                // level table

        for (int idx = t; idx < nsq; idx += 256) {
            int w = idx / nh, d = idx - w * nh;
            float a0 = Mp0[idx], a1 = Mp0[idx + ncb], a2 = Mp0[idx + 2*ncb];
            u32 h0 = ((u32)(a0*nf) ^ (((u32)(a1*nf))*2654435761u)
                                   ^ (((u32)(a2*nf))*805459861u)) & 255u;
            const float* t0 = tl + h0 * 3;
            float b0 = Mp1[idx], b1 = Mp1[idx + ncb], b2 = Mp1[idx + 2*ncb];
            u32 h1 = ((u32)(b0*nf) ^ (((u32)(b1*nf))*2654435761u)
                                   ^ (((u32)(b2*nf))*805459861u)) & 255u;
            const float* t1 = tl + h1 * 3;
            plane[d * pitch + w] = make_float4(lp(t0[0], t1[0], wp),
                                               lp(t0[1], t1[1], wp),
                                               lp(t0[2], t1[2], wp), 0.f);
        }
        __syncthreads();

        float* op = out + (size_t)b * 12582912 + (size_t)(3 * l) * 262144
                        + (size_t)i * 4096;
        #pragma unroll
        for (int it = 0; it < 4; ++it) {
            int pos = it * 256 + t;           // 0..1023
            int j = pos >> 4, d0 = (pos & 15) << 2;
            float fj = (float)j + 0.5f;
            float pr = fminf(fmaxf(fj * iv - 0.5f, 0.f), (float)(nh - 1));
            int r0 = min((int)pr, nh - 2);
            float wr = pr - (float)r0;
            const float4* P0 = plane + r0 * pitch;
            const float4* P1 = P0 + pitch;
            float ox[4], oy[4], oz[4];
            #pragma unroll
            for (int dd = 0; dd < 4; ++dd) {
                float fk = (float)(d0 + dd) + 0.5f;
                float pq = fminf(fmaxf(fk * iv - 0.5f, 0.f), (float)(nh - 1));
                int q0 = min((int)pq, nh - 2);
                float wq = pq - (float)q0;
                float4 A = P0[q0], B = P0[q0 + 1];
                float4 C = P1[q0], D = P1[q0 + 1];
                float tx = lp(A.x, B.x, wq), bx = lp(C.x, D.x, wq);
                float ty = lp(A.y, B.y, wq), by = lp(C.y, D.y, wq);
                float tz = lp(A.z, B.z, wq), bz = lp(C.z, D.z, wq);
                ox[dd] = lp(tx, bx, wr);
                oy[dd] = lp(ty, by, wr);
                oz[dd] = lp(tz, bz, wr);
            }
            int off = j * 64 + d0;
            st4(op + off,          ox[0], ox[1], ox[2], ox[3]);
            st4(op + off + 262144, oy[0], oy[1], oy[2], oy[3]);
            st4(op + off + 524288, oz[0], oz[1], oz[2], oz[3]);
        }
    } else {
        // ---- identity levels 12..15, j-half = l-12 ----
        float4* tab = shb;                    // [1024]
        float*  xs  = (float*)(shb + 1024);   // [3][64][33]
        const int jh = l - 12;

        for (int v = t; v < 1024; v += 256) {
            const float* te = tbl + (size_t)(3072 + v) * 3;   // (12*256+v)*3
            tab[v] = make_float4(te[0], te[1], te[2], 0.f);
        }
        const float* xp = x + (size_t)b * 786432 + (size_t)i * 4096 + jh * 32;
        #pragma unroll
        for (int c = 0; c < 3; ++c)
            for (int k = t; k < 2048; k += 256) {
                int w = k >> 5, jl = k & 31;
                xs[c * 2112 + w * 33 + jl] = xp[(size_t)c * 262144 + w * 64 + jl];
            }
        __syncthreads();

        float nfs[4] = {(float)hp.n[12], (float)hp.n[13],
                        (float)hp.n[14], (float)hp.n[15]};
        float* op = out + (size_t)b * 12582912 + (size_t)36 * 262144
                        + (size_t)i * 4096 + jh * 2048;   // jh*32*64

        #pragma unroll
        for (int it = 0; it < 2; ++it) {
            int pos = it * 256 + t;           // 0..511
            int jl = pos >> 4, d0 = (pos & 15) << 2;
            float xv[3][4];
            #pragma unroll
            for (int dd = 0; dd < 4; ++dd) {
                int wrow = (d0 + dd) * 33 + jl;
                xv[0][dd] = xs[wrow];
                xv[1][dd] = xs[2112 + wrow];
                xv[2][dd] = xs[4224 + wrow];
            }
            #pragma unroll
            for (int u = 0; u < 4; ++u) {
                float4 f[4];
                #pragma unroll
                for (int dd = 0; dd < 4; ++dd) {
                    u32 g0 = (u32)(xv[0][dd] * nfs[u]);
                    u32 g1 = ((u32)(xv[1][dd] * nfs[u])) * 2654435761u;
                    u32 g2 = ((u32)(xv[2][dd] * nfs[u])) * 805459861u;
                    f[dd] = tab[(u << 8) | ((g0 ^ g1 ^ g2) & 255u)];
                }
                int off = u * 786432 + jl * 64 + d0;    // u*3*262144
                st4(op + off,          f[0].x, f[1].x, f[2].x, f[3].x);
                st4(op + off + 262144, f[0].y, f[1].y, f[2].y, f[3].y);
                st4(op + off + 524288, f[0].z, f[1].z, f[2].z, f[3].z);
            }
        }
    }
}

// ---------------- host ----------------
extern "C" void kernel_launch(void* const* d_in, const int* in_sizes, int n_in,
                              void* d_out, int out_size, void* d_ws, size_t ws_size,
                              hipStream_t stream)
{
    const float* x   = (const float*)d_in[0];
    const float* tbl = (const float*)d_in[1];
    float* out = (float*)d_out;
    float* ws  = (float*)d_ws;

    // levels computed with the same libm (exp/log/pow) as the Python reference,
    // so the n=63-vs-64 boundary at l=15 matches bit-for-bit.
    HP hp;
    double growth = std::exp(std::log(16.0) / 15.0);
    for (int l = 0; l < 16; ++l)
        hp.n[l] = (int)std::floor(4.0 * std::pow(growth, (double)l));

    hipLaunchKernelGGL(k_pool_base, dim3(2052),    dim3(256), 0, stream, x, ws);
    hipLaunchKernelGGL(k_pyr,       dim3(471),     dim3(256), 0, stream, ws);
    hipLaunchKernelGGL(k_out,       dim3(256, 14), dim3(256), 0, stream, x, ws, tbl, out, hp);
}